// Round 13
// baseline (349.872 us; speedup 1.0000x reference)
//
#include <hip/hip_runtime.h>
#include <stdint.h>
#include <stddef.h>

#define NHEAD 16
#define DMODEL 1024
#define SS 2048
#define BB 2

typedef __attribute__((ext_vector_type(8))) short bf16x8;
typedef __attribute__((ext_vector_type(4))) float f32x4;
typedef __attribute__((ext_vector_type(4))) float floatv4;
typedef __attribute__((ext_vector_type(4))) unsigned short ushortv4;
typedef __attribute__((ext_vector_type(8))) unsigned short ushortv8;

#define MFMA16(A, B, C) __builtin_amdgcn_mfma_f32_16x16x32_bf16(A, B, C, 0, 0, 0)

__device__ __forceinline__ unsigned short f2bf(float f) {
    union { float f; unsigned u; } x;
    x.f = f;
    unsigned r = x.u + 0x7FFFu + ((x.u >> 16) & 1u);  // RNE
    return (unsigned short)(r >> 16);
}

__device__ __forceinline__ unsigned short f2bf_trunc(float f) {
    union { float f; unsigned u; } x;
    x.f = f;
    return (unsigned short)(x.u >> 16);
}

__device__ __forceinline__ float bf2f(unsigned short u) {
    union { unsigned u; float f; } x;
    x.u = ((unsigned)u) << 16;
    return x.f;
}

// ---------------- convert fp32 -> bf16 (q,k,v merged) ----------------
__global__ __launch_bounds__(256) void cvt3(const float* __restrict__ q,
                                            const float* __restrict__ k,
                                            const float* __restrict__ v,
                                            unsigned short* __restrict__ qb,
                                            unsigned short* __restrict__ kb,
                                            unsigned short* __restrict__ vb, int n4) {
    int i = blockIdx.x * 256 + threadIdx.x;
    if (i >= n4) return;
    const float* src = blockIdx.y == 0 ? q : (blockIdx.y == 1 ? k : v);
    unsigned short* dst = blockIdx.y == 0 ? qb : (blockIdx.y == 1 ? kb : vb);
    floatv4 x = ((const floatv4*)src)[i];
    ushortv4 o;
    o.x = f2bf(x.x); o.y = f2bf(x.y); o.z = f2bf(x.z); o.w = f2bf(x.w);
    ((ushortv4*)dst)[i] = o;
}

// ---------------- weight transpose + convert (Wq pre-scaled by 1/32) ----------------
__global__ __launch_bounds__(256) void wtrans4(
    const float* __restrict__ W0, const float* __restrict__ W1,
    const float* __restrict__ W2, const float* __restrict__ W3,
    unsigned short* __restrict__ T0, unsigned short* __restrict__ T1,
    unsigned short* __restrict__ T2, unsigned short* __restrict__ T3) {
    int sel = blockIdx.z;
    const float* W = sel == 0 ? W0 : (sel == 1 ? W1 : (sel == 2 ? W2 : W3));
    unsigned short* Wt = sel == 0 ? T0 : (sel == 1 ? T1 : (sel == 2 ? T2 : T3));
    float scl = (sel == 0) ? 0.03125f : 1.0f;
    __shared__ float tile[32][33];
    int tx = threadIdx.x & 31, ty = threadIdx.x >> 5;
    int nb = blockIdx.x * 32, kb = blockIdx.y * 32;
#pragma unroll
    for (int i = 0; i < 4; i++)
        tile[ty + i * 8][tx] = W[(size_t)(kb + ty + i * 8) * DMODEL + nb + tx];
    __syncthreads();
#pragma unroll
    for (int i = 0; i < 4; i++)
        Wt[(size_t)(nb + ty + i * 8) * DMODEL + kb + tx] = f2bf(tile[tx][ty + i * 8] * scl);
}

// ---------------- GEMM core: 128x128 tile, BK=64, 4 waves, swizzled LDS ----------------
__device__ __forceinline__ void stage_tile_sw(const unsigned short* __restrict__ src, int ld,
                                              unsigned short* lds) {
    int t = threadIdx.x;
#pragma unroll
    for (int i = 0; i < 4; i++) {
        int pos = i * 256 + t;            // 16B granule index
        int row = pos >> 3;
        int g = pos & 7;
        int kcol = (g ^ (row & 7)) * 8;   // inverse-swizzled source column
        __builtin_amdgcn_global_load_lds(
            (__attribute__((address_space(1))) void*)(src + row * ld + kcol),
            (__attribute__((address_space(3))) void*)(lds + pos * 8), 16, 0, 0);
    }
}

__device__ __forceinline__ bf16x8 frag_ld(const unsigned short* lds, int row, int koff) {
    int idx = row * 64 + (koff ^ ((row & 7) << 3));
    return *(const bf16x8*)(lds + idx);
}

__device__ __forceinline__ void gemm_core(const unsigned short* __restrict__ A,
                                          const unsigned short* __restrict__ Bt,
                                          int mbase, int nbase,
                                          unsigned short* As, unsigned short* Bs,
                                          f32x4 acc[4][4]) {
    int tid = threadIdx.x;
    int w = tid >> 6, lane = tid & 63, lg = lane >> 4, li = lane & 15;
    int wm = w >> 1, wn = w & 1;
#pragma unroll
    for (int mi = 0; mi < 4; mi++)
#pragma unroll
        for (int ni = 0; ni < 4; ni++) acc[mi][ni] = f32x4{0.f, 0.f, 0.f, 0.f};

    for (int ks = 0; ks < DMODEL / 64; ks++) {
        __syncthreads();
        stage_tile_sw(A + (size_t)mbase * DMODEL + ks * 64, DMODEL, As);
        stage_tile_sw(Bt + (size_t)nbase * DMODEL + ks * 64, DMODEL, Bs);
        __syncthreads();
        bf16x8 af[2][4], bfr[2][4];
#pragma unroll
        for (int kc = 0; kc < 2; kc++) {
#pragma unroll
            for (int mi = 0; mi < 4; mi++)
                af[kc][mi] = frag_ld(As, wm * 64 + mi * 16 + li, kc * 32 + lg * 8);
#pragma unroll
            for (int ni = 0; ni < 4; ni++)
                bfr[kc][ni] = frag_ld(Bs, wn * 64 + ni * 16 + li, kc * 32 + lg * 8);
        }
#pragma unroll
        for (int kc = 0; kc < 2; kc++)
#pragma unroll
            for (int mi = 0; mi < 4; mi++)
#pragma unroll
                for (int ni = 0; ni < 4; ni++)
                    acc[mi][ni] = MFMA16(af[kc][mi], bfr[kc][ni], acc[mi][ni]);
    }
}

#define CS_STRIDE 136  // 128 + 8 u16 pad

// ---------------- fused QKV projection; coalesced epilogue via LDS transpose ----------------
__global__ __launch_bounds__(256) void gemm_qkv(
    const unsigned short* __restrict__ qb, const unsigned short* __restrict__ kbuf,
    const unsigned short* __restrict__ vb,
    const unsigned short* __restrict__ Wqt, const unsigned short* __restrict__ Wkt,
    const unsigned short* __restrict__ Wvt,
    unsigned short* __restrict__ Qp, unsigned short* __restrict__ Kp,
    unsigned short* __restrict__ Vt) {
    __shared__ unsigned short LDSbuf[128 * CS_STRIDE];
    unsigned short* As = LDSbuf;
    unsigned short* Bs = LDSbuf + 128 * 64;
    unsigned short* Cs = LDSbuf;

    int bid = blockIdx.y * 24 + blockIdx.x;       // bijective XCD swizzle, nwg=768
    int nl = (bid & 7) * 96 + (bid >> 3);
    int nt = nl % 24;
    int mbase = (nl / 24) * 128;
    int seg = nt >> 3;
    int nbase = (nt & 7) * 128;
    const unsigned short* A = seg == 0 ? qb : (seg == 1 ? kbuf : vb);
    const unsigned short* Bt = seg == 0 ? Wqt : (seg == 1 ? Wkt : Wvt);

    f32x4 acc[4][4];
    gemm_core(A, Bt, mbase, nbase, As, Bs, acc);

    int tid = threadIdx.x, w = tid >> 6, lane = tid & 63, lg = lane >> 4, li = lane & 15;
    int wm = w >> 1, wn = w & 1;

    __syncthreads();
    if (seg == 2) {
#pragma unroll
        for (int mi = 0; mi < 4; mi++)
#pragma unroll
            for (int ni = 0; ni < 4; ni++) {
                int nloc = wn * 64 + ni * 16 + li;
                int mloc = wm * 64 + mi * 16 + lg * 4;
#pragma unroll
                for (int r = 0; r < 4; r++)
                    Cs[nloc * CS_STRIDE + mloc + r] = f2bf(acc[mi][ni][r]);
            }
        __syncthreads();
#pragma unroll
        for (int i = 0; i < 8; i++) {
            int g = i * 256 + tid;
            int nloc = g >> 4, mo = (g & 15) * 8;
            int ng = nbase + nloc, h = ng >> 6, d = ng & 63;
            int m0 = mbase + mo, b = m0 >> 11, s0 = m0 & 2047;
            *(ushortv8*)(Vt + (((size_t)((b * NHEAD + h) * 64 + d)) << 11) + s0) =
                *(const ushortv8*)(Cs + nloc * CS_STRIDE + mo);
        }
    } else {
        unsigned short* Out = seg == 0 ? Qp : Kp;
#pragma unroll
        for (int mi = 0; mi < 4; mi++)
#pragma unroll
            for (int ni = 0; ni < 4; ni++) {
                int nloc = wn * 64 + ni * 16 + li;
                int mloc = wm * 64 + mi * 16 + lg * 4;
#pragma unroll
                for (int r = 0; r < 4; r++)
                    Cs[(mloc + r) * CS_STRIDE + nloc] = f2bf(acc[mi][ni][r]);
            }
        __syncthreads();
#pragma unroll
        for (int i = 0; i < 8; i++) {
            int g = i * 256 + tid;
            int row = g >> 4, on = (g & 15) * 8;
            int ng = nbase + on, h = ng >> 6, d = ng & 63;
            int m0 = mbase + row, b = m0 >> 11, s0 = m0 & 2047;
            *(ushortv8*)(Out + ((size_t)((b * NHEAD + h) * SS + s0)) * 64 + d) =
                *(const ushortv8*)(Cs + row * CS_STRIDE + on);
        }
    }
}

// ---------------- output projection -> Yb bf16 (bias/residual folded into LN) ----------------
__global__ __launch_bounds__(256) void gemm_out(
    const unsigned short* __restrict__ Ob, const unsigned short* __restrict__ Wot,
    unsigned short* __restrict__ Yb) {
    __shared__ unsigned short LDSbuf[128 * CS_STRIDE];
    unsigned short* As = LDSbuf;
    unsigned short* Bs = LDSbuf + 128 * 64;
    unsigned short* Cs = LDSbuf;

    int bid = blockIdx.y * 8 + blockIdx.x;
    int nl = (bid & 7) * 32 + (bid >> 3);   // nwg=256
    int nbase = (nl % 8) * 128;
    int mbase = (nl / 8) * 128;

    f32x4 acc[4][4];
    gemm_core(Ob, Wot, mbase, nbase, As, Bs, acc);

    int tid = threadIdx.x, w = tid >> 6, lane = tid & 63, lg = lane >> 4, li = lane & 15;
    int wm = w >> 1, wn = w & 1;

    __syncthreads();
#pragma unroll
    for (int mi = 0; mi < 4; mi++)
#pragma unroll
        for (int ni = 0; ni < 4; ni++) {
            int nloc = wn * 64 + ni * 16 + li;
            int mloc = wm * 64 + mi * 16 + lg * 4;
#pragma unroll
            for (int r = 0; r < 4; r++)
                Cs[(mloc + r) * CS_STRIDE + nloc] = f2bf(acc[mi][ni][r]);
        }
    __syncthreads();
#pragma unroll
    for (int i = 0; i < 8; i++) {
        int g = i * 256 + tid;
        int row = g >> 4, on = (g & 15) * 8;
        *(ushortv8*)(Yb + (size_t)(mbase + row) * DMODEL + nbase + on) =
            *(const ushortv8*)(Cs + row * CS_STRIDE + on);
    }
}

// ---------------- attention pass A: flash O + linv (no stores in loop) ----------------
// grid 512 (XCD-bijective): 16 q-tiles(128) x 32 bh. 4 waves x (2 x 16) q-rows.
// bf16 mask bias (4KB) -> LDS 52KB -> 3 blocks/CU = 12 waves/CU.
__device__ __forceinline__ void stage_kv(const unsigned short* __restrict__ Kb,
                                         const unsigned short* __restrict__ Vtb, int s0,
                                         unsigned short* kl, unsigned short* vl, int tid) {
#pragma unroll
    for (int i = 0; i < 2; i++) {
        int pos = i * 256 + tid;          // 16B granule index, 512 = 64 rows x 8
        int row = pos >> 3, g = pos & 7;
        int col = (g ^ (row & 7)) * 8;    // inverse-swizzled source column
        __builtin_amdgcn_global_load_lds(
            (__attribute__((address_space(1))) void*)(Kb + (size_t)(s0 + row) * 64 + col),
            (__attribute__((address_space(3))) void*)(kl + pos * 8), 16, 0, 0);
    }
#pragma unroll
    for (int i = 0; i < 2; i++) {
        int pos = i * 256 + tid;
        int row = pos >> 3, g = pos & 7;
        int col = (g ^ (row & 7)) * 8;
        __builtin_amdgcn_global_load_lds(
            (__attribute__((address_space(1))) void*)(Vtb + (size_t)row * SS + s0 + col),
            (__attribute__((address_space(3))) void*)(vl + pos * 8), 16, 0, 0);
    }
}

__global__ __launch_bounds__(256, 3) void attn_o(
    const unsigned short* __restrict__ Qp, const unsigned short* __restrict__ Kp,
    const unsigned short* __restrict__ Vt, const int* __restrict__ mask,
    float* __restrict__ linvG, unsigned short* __restrict__ Ob) {
    __shared__ unsigned short Ks[2][64 * 64];   // 16KB
    __shared__ unsigned short Vs[2][64 * 64];   // 16KB
    __shared__ unsigned short Pl[4][32 * 64];   // 16KB
    __shared__ unsigned short Mlb[SS];          // bf16 additive mask bias (4KB)

    int blk = blockIdx.x;
    int xslot = blk & 7, rest = blk >> 3;
    int qt = rest & 15, bg = rest >> 4;
    int bh = bg * 8 + xslot, b = bh >> 4;
    int q0 = qt * 128;
    int tid = threadIdx.x, w = tid >> 6, lane = tid & 63, lg = lane >> 4, li = lane & 15;
    const unsigned short* Qb = Qp + (size_t)bh * SS * 64;
    const unsigned short* Kb = Kp + (size_t)bh * SS * 64;
    const unsigned short* Vtb = Vt + (size_t)bh * 64 * SS;
    const int* mb = mask + b * SS;
    int qw = q0 + w * 32;
    int sw = (li & 7) << 3;

    stage_kv(Kb, Vtb, 0, &Ks[0][0], &Vs[0][0], tid);

#pragma unroll
    for (int i = 0; i < SS / 256; i++) {
        int idx = i * 256 + tid;
        Mlb[idx] = mb[idx] ? (unsigned short)0 : f2bf_trunc(-1e10f);
    }

    bf16x8 qa[2][2];
#pragma unroll
    for (int fq = 0; fq < 2; fq++) {
        int q = qw + fq * 16 + li;
        qa[fq][0] = *(const bf16x8*)(Qb + (size_t)q * 64 + lg * 8);
        qa[fq][1] = *(const bf16x8*)(Qb + (size_t)q * 64 + 32 + lg * 8);
    }

    f32x4 oacc[2][4];
#pragma unroll
    for (int fq = 0; fq < 2; fq++)
#pragma unroll
        for (int gd = 0; gd < 4; gd++) oacc[fq][gd] = f32x4{0.f, 0.f, 0.f, 0.f};
    float lsA[2] = {0.f, 0.f}, lsB[2] = {0.f, 0.f};
    unsigned short* Pw = &Pl[w][0];

    asm volatile("s_waitcnt vmcnt(0) lgkmcnt(0)" ::: "memory");
    __builtin_amdgcn_s_barrier();

#pragma unroll 1
    for (int t = 0; t < 32; t++) {
        int k0 = t * 64;
        if (t + 1 < 32)
            stage_kv(Kb, Vtb, k0 + 64, &Ks[(t + 1) & 1][0], &Vs[(t + 1) & 1][0], tid);
        __builtin_amdgcn_sched_barrier(0);
        const unsigned short* Kc = &Ks[t & 1][0];
        const unsigned short* Vc = &Vs[t & 1][0];
#pragma unroll
        for (int fk = 0; fk < 4; fk++) {
            int row = fk * 16 + li;
            bf16x8 kf0 = *(const bf16x8*)(Kc + row * 64 + ((lg * 8) ^ sw));
            bf16x8 kf1 = *(const bf16x8*)(Kc + row * 64 + ((32 + lg * 8) ^ sw));
            ushortv4 mku = *(const ushortv4*)(Mlb + k0 + fk * 16 + lg * 4);
            float mkf[4];
#pragma unroll
            for (int r = 0; r < 4; r++) mkf[r] = bf2f(mku[r]);
#pragma unroll
            for (int fq = 0; fq < 2; fq++) {
                f32x4 sc = f32x4{0.f, 0.f, 0.f, 0.f};
                sc = MFMA16(kf0, qa[fq][0], sc);
                sc = MFMA16(kf1, qa[fq][1], sc);
                floatv4 pv;
#pragma unroll
                for (int r = 0; r < 4; r++)
                    pv[r] = __expf(fminf(sc[r] + mkf[r], 80.f));
                lsA[fq] += pv[0] + pv[1];
                lsB[fq] += pv[2] + pv[3];
                ushortv4 pk;
#pragma unroll
                for (int r = 0; r < 4; r++) pk[r] = f2bf_trunc(pv[r]);
                *(ushortv4*)(Pw + (fq * 16 + li) * 64 + ((fk * 16 + lg * 4) ^ sw)) = pk;
            }
        }
        // PV: vf reads shared across both fq sub-tiles
#pragma unroll
        for (int kc = 0; kc < 2; kc++) {
            bf16x8 vf[4];
#pragma unroll
            for (int gd = 0; gd < 4; gd++) {
                int vrow = gd * 16 + li;
                vf[gd] = *(const bf16x8*)(Vc + vrow * 64 + ((kc * 32 + lg * 8) ^ sw));
            }
#pragma unroll
            for (int fq = 0; fq < 2; fq++) {
                bf16x8 pa = *(const bf16x8*)(Pw + (fq * 16 + li) * 64 +
                                             ((kc * 32 + lg * 8) ^ sw));
#pragma unroll
                for (int gd = 0; gd < 4; gd++)
                    oacc[fq][gd] = MFMA16(pa, vf[gd], oacc[fq][gd]);
            }
        }
        asm volatile("s_waitcnt vmcnt(0)" ::: "memory");
        __builtin_amdgcn_s_barrier();
    }

    // linv per (fq, li); broadcast to D-layout rows via per-wave LDS
    float linvv[2];
    float* LinvW = (float*)Pw;  // Pl[w] dead now
#pragma unroll
    for (int fq = 0; fq < 2; fq++) {
        float lsum = lsA[fq] + lsB[fq];
        lsum += __shfl_xor(lsum, 16);
        lsum += __shfl_xor(lsum, 32);
        linvv[fq] = 1.0f / lsum;
        if (lg == 0) {
            LinvW[fq * 16 + li] = linvv[fq];
            linvG[(size_t)bh * SS + qw + fq * 16 + li] = linvv[fq];
        }
    }
    int h = bh & 15;
#pragma unroll
    for (int fq = 0; fq < 2; fq++)
#pragma unroll
        for (int gd = 0; gd < 4; gd++)
#pragma unroll
            for (int r = 0; r < 4; r++) {
                int srow = qw + fq * 16 + lg * 4 + r;
                float o = oacc[fq][gd][r] * LinvW[fq * 16 + lg * 4 + r];
                Ob[(size_t)(b * SS + srow) * DMODEL + h * 64 + gd * 16 + li] = f2bf(o);
            }
}

// ---------------- attention pass B: P writer, k-sliced for occupancy ----------------
// grid 2048 (XCD-bijective on bh): 16 qt x 4 ksl x 4 bg x 8 xslot.
// Each block: 128 q-rows x 512 k. 2KB LDS -> VGPR-bound occupancy (~6-8 blocks/CU),
// many concurrent load->MFMA->exp->store streams; stores self-pace at write BW.
__global__ __launch_bounds__(256) void attn_p(
    const unsigned short* __restrict__ Qp, const unsigned short* __restrict__ Kp,
    const int* __restrict__ mask, const float* __restrict__ linvG,
    float* __restrict__ attn_out) {
    __shared__ float Ml[512];
    int blk = blockIdx.x;
    int xslot = blk & 7, rest = blk >> 3;
    int qt = rest & 15; rest >>= 4;
    int ksl = rest & 3; rest >>= 2;
    int bg = rest;                       // 0..3
    int bh = bg * 8 + xslot, b = bh >> 4;
    int q0 = qt * 128;
    int kbase = ksl * 512;
    int tid = threadIdx.x, w = tid >> 6, lane = tid & 63, lg = lane >> 4, li = lane & 15;
    const unsigned short* Qb = Qp + (size_t)bh * SS * 64;
    const unsigned short* Kb = Kp + (size_t)bh * SS * 64;
    const int* mb = mask + b * SS + kbase;
    int qw = q0 + w * 32;

#pragma unroll
    for (int i = 0; i < 2; i++) {
        int idx = i * 256 + tid;
        Ml[idx] = mb[idx] ? 0.f : -1e10f;
    }
    __syncthreads();

    bf16x8 qa[2][2];
    float lv[2];
#pragma unroll
    for (int fq = 0; fq < 2; fq++) {
        int q = qw + fq * 16 + li;
        qa[fq][0] = *(const bf16x8*)(Qb + (size_t)q * 64 + lg * 8);
        qa[fq][1] = *(const bf16x8*)(Qb + (size_t)q * 64 + 32 + lg * 8);
        lv[fq] = linvG[(size_t)bh * SS + q];
    }
    float* ar0 = attn_out + ((size_t)bh * SS + qw + li) * SS + kbase + lg * 4;
    float* ar1 = ar0 + (size_t)16 * SS;

#pragma unroll 1
    for (int kt = 0; kt < 4; kt++) {
        int k0 = kt * 128;
#pragma unroll
        for (int fk = 0; fk < 8; fk++) {
            const unsigned short* kp = Kb + (size_t)(kbase + k0 + fk * 16 + li) * 64;
            bf16x8 kf0 = *(const bf16x8*)(kp + lg * 8);
            bf16x8 kf1 = *(const bf16x8*)(kp + 32 + lg * 8);
            floatv4 mk = *(const floatv4*)(Ml + k0 + fk * 16 + lg * 4);
#pragma unroll
            for (int fq = 0; fq < 2; fq++) {
                f32x4 sc = f32x4{0.f, 0.f, 0.f, 0.f};
                sc = MFMA16(kf0, qa[fq][0], sc);
                sc = MFMA16(kf1, qa[fq][1], sc);
                floatv4 pv;
#pragma unroll
                for (int r = 0; r < 4; r++)
                    pv[r] = __expf(fminf(sc[r] + mk[r], 80.f)) * lv[fq];
                *(floatv4*)((fq == 0 ? ar0 : ar1) + k0 + fk * 16) = pv;
            }
        }
    }
}

// ---------------- LayerNorm (bias + residual folded in; Yb is bf16) ----------------
__global__ __launch_bounds__(256) void ln_kernel(const unsigned short* __restrict__ Yb,
                                                 const float* __restrict__ qres,
                                                 const float* __restrict__ bo,
                                                 const float* __restrict__ gamma,
                                                 const float* __restrict__ beta,
                                                 float* __restrict__ out) {
    int row = blockIdx.x;
    int t = threadIdx.x;
    ushortv4 yv = ((const ushortv4*)(Yb + (size_t)row * DMODEL))[t];
    floatv4 qv = ((const floatv4*)(qres + (size_t)row * DMODEL))[t];
    floatv4 bv = ((const floatv4*)bo)[t];
    floatv4 v;
    v.x = bf2f(yv.x) + bv.x + qv.x;
    v.y = bf2f(yv.y) + bv.y + qv.y;
    v.z = bf2f(yv.z) + bv.z + qv.z;
    v.w = bf2f(yv.w) + bv.w + qv.w;
    float s1 = v.x + v.y + v.z + v.w;
    float s2 = v.x * v.x + v.y * v.y + v.z * v.z + v.w * v.w;
#pragma unroll
    for (int m = 1; m < 64; m <<= 1) { s1 += __shfl_xor(s1, m); s2 += __shfl_xor(s2, m); }
    __shared__ float red[8];
    int w = t >> 6, lane = t & 63;
    if (lane == 0) { red[w] = s1; red[4 + w] = s2; }
    __syncthreads();
    s1 = red[0] + red[1] + red[2] + red[3];
    s2 = red[4] + red[5] + red[6] + red[7];
    float mu = s1 * (1.0f / DMODEL);
    float var = s2 * (1.0f / DMODEL) - mu * mu;
    float rstd = rsqrtf(var + 1e-5f);
    floatv4 g = ((const floatv4*)gamma)[t];
    floatv4 bb = ((const floatv4*)beta)[t];
    floatv4 o;
    o.x = (v.x - mu) * rstd * g.x + bb.x;
    o.y = (v.y - mu) * rstd * g.y + bb.y;
    o.z = (v.z - mu) * rstd * g.z + bb.z;
    o.w = (v.w - mu) * rstd * g.w + bb.w;
    ((floatv4*)(out + (size_t)row * DMODEL))[t] = o;
}

// ---------------- launch ----------------
extern "C" void kernel_launch(void* const* d_in, const int* in_sizes, int n_in,
                              void* d_out, int out_size, void* d_ws, size_t ws_size,
                              hipStream_t stream) {
    const float* q = (const float*)d_in[0];
    const float* k = (const float*)d_in[1];
    const float* v = (const float*)d_in[2];
    const int* mask = (const int*)d_in[3];
    const float* Wq = (const float*)d_in[4];
    const float* Wk = (const float*)d_in[5];
    const float* Wv = (const float*)d_in[6];
    const float* Wo = (const float*)d_in[7];
    const float* bo = (const float*)d_in[8];
    const float* gamma = (const float*)d_in[9];
    const float* beta = (const float*)d_in[10];

    float* out = (float*)d_out;
    float* attn = out + (size_t)BB * SS * DMODEL;

    const size_t NTOK = (size_t)BB * SS;          // 4096
    unsigned short* qb = (unsigned short*)d_ws;   // [4096][1024] bf16
    unsigned short* kb = qb + NTOK * DMODEL;
    unsigned short* vb = kb + NTOK * DMODEL;
    unsigned short* Wqt = vb + NTOK * DMODEL;     // [1024][1024] bf16 (transposed)
    unsigned short* Wkt = Wqt + (size_t)DMODEL * DMODEL;
    unsigned short* Wvt = Wkt + (size_t)DMODEL * DMODEL;
    unsigned short* Wot = Wvt + (size_t)DMODEL * DMODEL;
    unsigned short* Qp = Wot + (size_t)DMODEL * DMODEL;  // [B,H,S,64] bf16 (pre-scaled)
    unsigned short* Kp = Qp + NTOK * DMODEL;
    unsigned short* Vt = Kp + NTOK * DMODEL;      // [B,H,64,S] bf16 (transposed)
    unsigned short* Ob = Vt + NTOK * DMODEL;      // [4096][1024] bf16
    float* linvG = (float*)(Ob + NTOK * DMODEL);  // [32][2048] f32
    unsigned short* Yb = qb;                      // reuse qb region post-attention (bf16)

    const int n4 = (int)(NTOK * DMODEL / 4);
    cvt3<<<dim3(n4 / 256, 3), 256, 0, stream>>>(q, k, v, qb, kb, vb, n4);
    wtrans4<<<dim3(32, 32, 4), 256, 0, stream>>>(Wq, Wk, Wv, Wo, Wqt, Wkt, Wvt, Wot);

    gemm_qkv<<<dim3(24, 32), 256, 0, stream>>>(qb, kb, vb, Wqt, Wkt, Wvt, Qp, Kp, Vt);

    attn_o<<<512, 256, 0, stream>>>(Qp, Kp, Vt, mask, linvG, Ob);
    attn_p<<<2048, 256, 0, stream>>>(Qp, Kp, mask, linvG, attn);

    gemm_out<<<dim3(8, 32), 256, 0, stream>>>(Ob, Wot, Yb);

    ln_kernel<<<(int)NTOK, 256, 0, stream>>>(Yb, q, bo, gamma, beta, out);
}

// Round 14
// 277.050 us; speedup vs baseline: 1.2628x; 1.2628x over previous
//
#include <hip/hip_runtime.h>
#include <stdint.h>
#include <stddef.h>

#define NHEAD 16
#define DMODEL 1024
#define SS 2048
#define BB 2

typedef __attribute__((ext_vector_type(8))) short bf16x8;
typedef __attribute__((ext_vector_type(4))) float f32x4;
typedef __attribute__((ext_vector_type(4))) float floatv4;
typedef __attribute__((ext_vector_type(4))) unsigned short ushortv4;
typedef __attribute__((ext_vector_type(8))) unsigned short ushortv8;

#define MFMA16(A, B, C) __builtin_amdgcn_mfma_f32_16x16x32_bf16(A, B, C, 0, 0, 0)

__device__ __forceinline__ unsigned short f2bf(float f) {
    union { float f; unsigned u; } x;
    x.f = f;
    unsigned r = x.u + 0x7FFFu + ((x.u >> 16) & 1u);  // RNE
    return (unsigned short)(r >> 16);
}

__device__ __forceinline__ unsigned short f2bf_trunc(float f) {
    union { float f; unsigned u; } x;
    x.f = f;
    return (unsigned short)(x.u >> 16);
}

__device__ __forceinline__ float bf2f(unsigned short u) {
    union { unsigned u; float f; } x;
    x.u = ((unsigned)u) << 16;
    return x.f;
}

// ---------------- prep: cvt3 + wtrans4 merged into one launch ----------------
// blocks [0,12288): q/k/v f32->bf16 (4096 blocks each)
// blocks [12288,16384): 4 weight transposes (1024 blocks each); Wq pre-scaled 1/32
__global__ __launch_bounds__(256) void prep(
    const float* __restrict__ q, const float* __restrict__ k, const float* __restrict__ v,
    unsigned short* __restrict__ qb, unsigned short* __restrict__ kb,
    unsigned short* __restrict__ vb,
    const float* __restrict__ W0, const float* __restrict__ W1,
    const float* __restrict__ W2, const float* __restrict__ W3,
    unsigned short* __restrict__ T0, unsigned short* __restrict__ T1,
    unsigned short* __restrict__ T2, unsigned short* __restrict__ T3) {
    __shared__ float tile[32][33];
    int blk = blockIdx.x;
    if (blk < 12288) {
        int which = blk >> 12;
        int i = (blk & 4095) * 256 + threadIdx.x;
        const float* src = which == 0 ? q : (which == 1 ? k : v);
        unsigned short* dst = which == 0 ? qb : (which == 1 ? kb : vb);
        floatv4 x = ((const floatv4*)src)[i];
        ushortv4 o;
        o.x = f2bf(x.x); o.y = f2bf(x.y); o.z = f2bf(x.z); o.w = f2bf(x.w);
        ((ushortv4*)dst)[i] = o;
    } else {
        int t = blk - 12288;
        int sel = t >> 10;
        int rest = t & 1023;
        const float* W = sel == 0 ? W0 : (sel == 1 ? W1 : (sel == 2 ? W2 : W3));
        unsigned short* Wt = sel == 0 ? T0 : (sel == 1 ? T1 : (sel == 2 ? T2 : T3));
        float scl = (sel == 0) ? 0.03125f : 1.0f;
        int tx = threadIdx.x & 31, ty = threadIdx.x >> 5;
        int nb = (rest & 31) * 32, kb2 = (rest >> 5) * 32;
#pragma unroll
        for (int i = 0; i < 4; i++)
            tile[ty + i * 8][tx] = W[(size_t)(kb2 + ty + i * 8) * DMODEL + nb + tx];
        __syncthreads();
#pragma unroll
        for (int i = 0; i < 4; i++)
            Wt[(size_t)(nb + ty + i * 8) * DMODEL + kb2 + tx] =
                f2bf(tile[tx][ty + i * 8] * scl);
    }
}

// ---------------- GEMM core: 128x128 tile, BK=64, 4 waves, swizzled LDS ----------------
__device__ __forceinline__ void stage_tile_sw(const unsigned short* __restrict__ src, int ld,
                                              unsigned short* lds) {
    int t = threadIdx.x;
#pragma unroll
    for (int i = 0; i < 4; i++) {
        int pos = i * 256 + t;            // 16B granule index
        int row = pos >> 3;
        int g = pos & 7;
        int kcol = (g ^ (row & 7)) * 8;   // inverse-swizzled source column
        __builtin_amdgcn_global_load_lds(
            (__attribute__((address_space(1))) void*)(src + row * ld + kcol),
            (__attribute__((address_space(3))) void*)(lds + pos * 8), 16, 0, 0);
    }
}

__device__ __forceinline__ bf16x8 frag_ld(const unsigned short* lds, int row, int koff) {
    int idx = row * 64 + (koff ^ ((row & 7) << 3));
    return *(const bf16x8*)(lds + idx);
}

__device__ __forceinline__ void gemm_core(const unsigned short* __restrict__ A,
                                          const unsigned short* __restrict__ Bt,
                                          int mbase, int nbase,
                                          unsigned short* As, unsigned short* Bs,
                                          f32x4 acc[4][4]) {
    int tid = threadIdx.x;
    int w = tid >> 6, lane = tid & 63, lg = lane >> 4, li = lane & 15;
    int wm = w >> 1, wn = w & 1;
#pragma unroll
    for (int mi = 0; mi < 4; mi++)
#pragma unroll
        for (int ni = 0; ni < 4; ni++) acc[mi][ni] = f32x4{0.f, 0.f, 0.f, 0.f};

    for (int ks = 0; ks < DMODEL / 64; ks++) {
        __syncthreads();
        stage_tile_sw(A + (size_t)mbase * DMODEL + ks * 64, DMODEL, As);
        stage_tile_sw(Bt + (size_t)nbase * DMODEL + ks * 64, DMODEL, Bs);
        __syncthreads();
        bf16x8 af[2][4], bfr[2][4];
#pragma unroll
        for (int kc = 0; kc < 2; kc++) {
#pragma unroll
            for (int mi = 0; mi < 4; mi++)
                af[kc][mi] = frag_ld(As, wm * 64 + mi * 16 + li, kc * 32 + lg * 8);
#pragma unroll
            for (int ni = 0; ni < 4; ni++)
                bfr[kc][ni] = frag_ld(Bs, wn * 64 + ni * 16 + li, kc * 32 + lg * 8);
        }
#pragma unroll
        for (int kc = 0; kc < 2; kc++)
#pragma unroll
            for (int mi = 0; mi < 4; mi++)
#pragma unroll
                for (int ni = 0; ni < 4; ni++)
                    acc[mi][ni] = MFMA16(af[kc][mi], bfr[kc][ni], acc[mi][ni]);
    }
}

#define CS_STRIDE 136  // 128 + 8 u16 pad

// ---------------- fused QKV projection; coalesced epilogue via LDS transpose ----------------
__global__ __launch_bounds__(256) void gemm_qkv(
    const unsigned short* __restrict__ qb, const unsigned short* __restrict__ kbuf,
    const unsigned short* __restrict__ vb,
    const unsigned short* __restrict__ Wqt, const unsigned short* __restrict__ Wkt,
    const unsigned short* __restrict__ Wvt,
    unsigned short* __restrict__ Qp, unsigned short* __restrict__ Kp,
    unsigned short* __restrict__ Vt) {
    __shared__ unsigned short LDSbuf[128 * CS_STRIDE];
    unsigned short* As = LDSbuf;
    unsigned short* Bs = LDSbuf + 128 * 64;
    unsigned short* Cs = LDSbuf;

    int bid = blockIdx.y * 24 + blockIdx.x;       // bijective XCD swizzle, nwg=768
    int nl = (bid & 7) * 96 + (bid >> 3);
    int nt = nl % 24;
    int mbase = (nl / 24) * 128;
    int seg = nt >> 3;
    int nbase = (nt & 7) * 128;
    const unsigned short* A = seg == 0 ? qb : (seg == 1 ? kbuf : vb);
    const unsigned short* Bt = seg == 0 ? Wqt : (seg == 1 ? Wkt : Wvt);

    f32x4 acc[4][4];
    gemm_core(A, Bt, mbase, nbase, As, Bs, acc);

    int tid = threadIdx.x, w = tid >> 6, lane = tid & 63, lg = lane >> 4, li = lane & 15;
    int wm = w >> 1, wn = w & 1;

    __syncthreads();
    if (seg == 2) {
#pragma unroll
        for (int mi = 0; mi < 4; mi++)
#pragma unroll
            for (int ni = 0; ni < 4; ni++) {
                int nloc = wn * 64 + ni * 16 + li;
                int mloc = wm * 64 + mi * 16 + lg * 4;
#pragma unroll
                for (int r = 0; r < 4; r++)
                    Cs[nloc * CS_STRIDE + mloc + r] = f2bf(acc[mi][ni][r]);
            }
        __syncthreads();
#pragma unroll
        for (int i = 0; i < 8; i++) {
            int g = i * 256 + tid;
            int nloc = g >> 4, mo = (g & 15) * 8;
            int ng = nbase + nloc, h = ng >> 6, d = ng & 63;
            int m0 = mbase + mo, b = m0 >> 11, s0 = m0 & 2047;
            *(ushortv8*)(Vt + (((size_t)((b * NHEAD + h) * 64 + d)) << 11) + s0) =
                *(const ushortv8*)(Cs + nloc * CS_STRIDE + mo);
        }
    } else {
        unsigned short* Out = seg == 0 ? Qp : Kp;
#pragma unroll
        for (int mi = 0; mi < 4; mi++)
#pragma unroll
            for (int ni = 0; ni < 4; ni++) {
                int nloc = wn * 64 + ni * 16 + li;
                int mloc = wm * 64 + mi * 16 + lg * 4;
#pragma unroll
                for (int r = 0; r < 4; r++)
                    Cs[(mloc + r) * CS_STRIDE + nloc] = f2bf(acc[mi][ni][r]);
            }
        __syncthreads();
#pragma unroll
        for (int i = 0; i < 8; i++) {
            int g = i * 256 + tid;
            int row = g >> 4, on = (g & 15) * 8;
            int ng = nbase + on, h = ng >> 6, d = ng & 63;
            int m0 = mbase + row, b = m0 >> 11, s0 = m0 & 2047;
            *(ushortv8*)(Out + ((size_t)((b * NHEAD + h) * SS + s0)) * 64 + d) =
                *(const ushortv8*)(Cs + row * CS_STRIDE + on);
        }
    }
}

// ---------------- output projection -> Yb bf16 (bias/residual folded into LN) ----------------
__global__ __launch_bounds__(256) void gemm_out(
    const unsigned short* __restrict__ Ob, const unsigned short* __restrict__ Wot,
    unsigned short* __restrict__ Yb) {
    __shared__ unsigned short LDSbuf[128 * CS_STRIDE];
    unsigned short* As = LDSbuf;
    unsigned short* Bs = LDSbuf + 128 * 64;
    unsigned short* Cs = LDSbuf;

    int bid = blockIdx.y * 8 + blockIdx.x;
    int nl = (bid & 7) * 32 + (bid >> 3);   // nwg=256
    int nbase = (nl % 8) * 128;
    int mbase = (nl / 8) * 128;

    f32x4 acc[4][4];
    gemm_core(Ob, Wot, mbase, nbase, As, Bs, acc);

    int tid = threadIdx.x, w = tid >> 6, lane = tid & 63, lg = lane >> 4, li = lane & 15;
    int wm = w >> 1, wn = w & 1;

    __syncthreads();
#pragma unroll
    for (int mi = 0; mi < 4; mi++)
#pragma unroll
        for (int ni = 0; ni < 4; ni++) {
            int nloc = wn * 64 + ni * 16 + li;
            int mloc = wm * 64 + mi * 16 + lg * 4;
#pragma unroll
            for (int r = 0; r < 4; r++)
                Cs[(mloc + r) * CS_STRIDE + nloc] = f2bf(acc[mi][ni][r]);
        }
    __syncthreads();
#pragma unroll
    for (int i = 0; i < 8; i++) {
        int g = i * 256 + tid;
        int row = g >> 4, on = (g & 15) * 8;
        *(ushortv8*)(Yb + (size_t)(mbase + row) * DMODEL + nbase + on) =
            *(const ushortv8*)(Cs + row * CS_STRIDE + on);
    }
}

// ---------------- fused attention (R11 structure + LDS-coalesced P stores) ----------------
// grid 512 (XCD-bijective): 16 q-tiles(128) x 32 bh. 4 waves x (2 x 16) q-rows.
// Pass A: K/V dbuf via global_load_lds, f32 mask bias in LDS, no stores in loop.
// Pass B: recompute scores (K from L2), normalize by in-register linv, route P
// through a per-wave f32 LDS tile (overlaid on dead Ks/Vs) and store with
// 4 rows x 256B contiguous per instruction.
__device__ __forceinline__ void stage_kv(const unsigned short* __restrict__ Kb,
                                         const unsigned short* __restrict__ Vtb, int s0,
                                         unsigned short* kl, unsigned short* vl, int tid) {
#pragma unroll
    for (int i = 0; i < 2; i++) {
        int pos = i * 256 + tid;          // 16B granule index, 512 = 64 rows x 8
        int row = pos >> 3, g = pos & 7;
        int col = (g ^ (row & 7)) * 8;    // inverse-swizzled source column
        __builtin_amdgcn_global_load_lds(
            (__attribute__((address_space(1))) void*)(Kb + (size_t)(s0 + row) * 64 + col),
            (__attribute__((address_space(3))) void*)(kl + pos * 8), 16, 0, 0);
    }
#pragma unroll
    for (int i = 0; i < 2; i++) {
        int pos = i * 256 + tid;
        int row = pos >> 3, g = pos & 7;
        int col = (g ^ (row & 7)) * 8;
        __builtin_amdgcn_global_load_lds(
            (__attribute__((address_space(1))) void*)(Vtb + (size_t)row * SS + s0 + col),
            (__attribute__((address_space(3))) void*)(vl + pos * 8), 16, 0, 0);
    }
}

__global__ __launch_bounds__(256, 2) void attn_fused(
    const unsigned short* __restrict__ Qp, const unsigned short* __restrict__ Kp,
    const unsigned short* __restrict__ Vt, const int* __restrict__ mask,
    float* __restrict__ attn_out, unsigned short* __restrict__ Ob) {
    __shared__ __align__(16) unsigned short SH[28672];  // 56KB carved below
    unsigned short* KsB = SH;                  // [2][64*64]   (16KB)
    unsigned short* VsB = SH + 8192;           // [2][64*64]   (16KB)
    unsigned short* PlB = SH + 16384;          // [4][32*64]   (16KB)
    float* Ml = (float*)(SH + 24576);          // [2048]       (8KB)

    int blk = blockIdx.x;
    int xslot = blk & 7, rest = blk >> 3;
    int qt = rest & 15, bg = rest >> 4;
    int bh = bg * 8 + xslot, b = bh >> 4;
    int q0 = qt * 128;
    int tid = threadIdx.x, w = tid >> 6, lane = tid & 63, lg = lane >> 4, li = lane & 15;
    const unsigned short* Qb = Qp + (size_t)bh * SS * 64;
    const unsigned short* Kb = Kp + (size_t)bh * SS * 64;
    const unsigned short* Vtb = Vt + (size_t)bh * 64 * SS;
    const int* mb = mask + b * SS;
    int qw = q0 + w * 32;
    int sw = (li & 7) << 3;

    stage_kv(Kb, Vtb, 0, KsB, VsB, tid);

#pragma unroll
    for (int i = 0; i < SS / 256; i++) {
        int idx = i * 256 + tid;
        Ml[idx] = mb[idx] ? 0.f : -1e10f;
    }

    bf16x8 qa[2][2];
#pragma unroll
    for (int fq = 0; fq < 2; fq++) {
        int q = qw + fq * 16 + li;
        qa[fq][0] = *(const bf16x8*)(Qb + (size_t)q * 64 + lg * 8);
        qa[fq][1] = *(const bf16x8*)(Qb + (size_t)q * 64 + 32 + lg * 8);
    }

    f32x4 oacc[2][4];
#pragma unroll
    for (int fq = 0; fq < 2; fq++)
#pragma unroll
        for (int gd = 0; gd < 4; gd++) oacc[fq][gd] = f32x4{0.f, 0.f, 0.f, 0.f};
    float lsA[2] = {0.f, 0.f}, lsB[2] = {0.f, 0.f};
    unsigned short* Pw = PlB + w * (32 * 64);

    asm volatile("s_waitcnt vmcnt(0) lgkmcnt(0)" ::: "memory");
    __builtin_amdgcn_s_barrier();

#pragma unroll 1
    for (int t = 0; t < 32; t++) {
        int k0 = t * 64;
        if (t + 1 < 32)
            stage_kv(Kb, Vtb, k0 + 64, KsB + ((t + 1) & 1) * 4096,
                     VsB + ((t + 1) & 1) * 4096, tid);
        __builtin_amdgcn_sched_barrier(0);
        const unsigned short* Kc = KsB + (t & 1) * 4096;
        const unsigned short* Vc = VsB + (t & 1) * 4096;
#pragma unroll
        for (int fk = 0; fk < 4; fk++) {
            int row = fk * 16 + li;
            bf16x8 kf0 = *(const bf16x8*)(Kc + row * 64 + ((lg * 8) ^ sw));
            bf16x8 kf1 = *(const bf16x8*)(Kc + row * 64 + ((32 + lg * 8) ^ sw));
            floatv4 mk = *(const floatv4*)(Ml + k0 + fk * 16 + lg * 4);
#pragma unroll
            for (int fq = 0; fq < 2; fq++) {
                f32x4 sc = f32x4{0.f, 0.f, 0.f, 0.f};
                sc = MFMA16(kf0, qa[fq][0], sc);
                sc = MFMA16(kf1, qa[fq][1], sc);
                floatv4 pv;
#pragma unroll
                for (int r = 0; r < 4; r++)
                    pv[r] = __expf(fminf(sc[r] + mk[r], 80.f));
                lsA[fq] += pv[0] + pv[1];
                lsB[fq] += pv[2] + pv[3];
                ushortv4 pk;
#pragma unroll
                for (int r = 0; r < 4; r++) pk[r] = f2bf_trunc(pv[r]);
                *(ushortv4*)(Pw + (fq * 16 + li) * 64 + ((fk * 16 + lg * 4) ^ sw)) = pk;
            }
        }
        // PV: vf reads shared across both fq sub-tiles
#pragma unroll
        for (int kc = 0; kc < 2; kc++) {
            bf16x8 vf[4];
#pragma unroll
            for (int gd = 0; gd < 4; gd++) {
                int vrow = gd * 16 + li;
                vf[gd] = *(const bf16x8*)(Vc + vrow * 64 + ((kc * 32 + lg * 8) ^ sw));
            }
#pragma unroll
            for (int fq = 0; fq < 2; fq++) {
                bf16x8 pa = *(const bf16x8*)(Pw + (fq * 16 + li) * 64 +
                                             ((kc * 32 + lg * 8) ^ sw));
#pragma unroll
                for (int gd = 0; gd < 4; gd++)
                    oacc[fq][gd] = MFMA16(pa, vf[gd], oacc[fq][gd]);
            }
        }
        asm volatile("s_waitcnt vmcnt(0)" ::: "memory");
        __builtin_amdgcn_s_barrier();
    }

    // linv per (fq, li); broadcast to D-layout rows via per-wave LDS
    float linvv[2];
    float* LinvW = (float*)Pw;  // Pl[w] dead now
#pragma unroll
    for (int fq = 0; fq < 2; fq++) {
        float lsum = lsA[fq] + lsB[fq];
        lsum += __shfl_xor(lsum, 16);
        lsum += __shfl_xor(lsum, 32);
        linvv[fq] = 1.0f / lsum;
        if (lg == 0) LinvW[fq * 16 + li] = linvv[fq];
    }
    int h = bh & 15;
#pragma unroll
    for (int fq = 0; fq < 2; fq++)
#pragma unroll
        for (int gd = 0; gd < 4; gd++)
#pragma unroll
            for (int r = 0; r < 4; r++) {
                int srow = qw + fq * 16 + lg * 4 + r;
                float o = oacc[fq][gd][r] * LinvW[fq * 16 + lg * 4 + r];
                Ob[(size_t)(b * SS + srow) * DMODEL + h * 64 + gd * 16 + li] = f2bf(o);
            }

    // ---- pass B: stream normalized P via per-wave LDS transpose (coalesced) ----
    // Pt overlays Ks+Vs (dead after pass A); 8KB (32x64 f32) per wave.
    __builtin_amdgcn_s_barrier();  // all waves past last PV reads of Ks/Vs
    float* Pt = (float*)SH + w * 2048;
    int rgrp = lane >> 4;  // 0..3

#pragma unroll 1
    for (int t = 0; t < 32; t++) {
        int k0 = t * 64;
#pragma unroll
        for (int fk = 0; fk < 4; fk++) {
            const unsigned short* kp = Kb + (size_t)(k0 + fk * 16 + li) * 64;
            bf16x8 kf0 = *(const bf16x8*)(kp + lg * 8);
            bf16x8 kf1 = *(const bf16x8*)(kp + 32 + lg * 8);
            floatv4 mk = *(const floatv4*)(Ml + k0 + fk * 16 + lg * 4);
#pragma unroll
            for (int fq = 0; fq < 2; fq++) {
                f32x4 sc = f32x4{0.f, 0.f, 0.f, 0.f};
                sc = MFMA16(kf0, qa[fq][0], sc);
                sc = MFMA16(kf1, qa[fq][1], sc);
                floatv4 pv;
#pragma unroll
                for (int r = 0; r < 4; r++)
                    pv[r] = __expf(fminf(sc[r] + mk[r], 80.f)) * linvv[fq];
                int prow = fq * 16 + li;
                *(floatv4*)(Pt + prow * 64 + ((fk * 16 + lg * 4) ^ ((prow & 7) << 3))) = pv;
            }
        }
        // readback + coalesced store: 4 rows x 256B contiguous per instruction
#pragma unroll
        for (int g = 0; g < 8; g++) {
            int row = g * 4 + rgrp;
            int colb = li * 4;
            floatv4 vv = *(const floatv4*)(Pt + row * 64 + (colb ^ ((row & 7) << 3)));
            *(floatv4*)(attn_out + ((size_t)bh * SS + qw + row) * SS + k0 + colb) = vv;
        }
    }
}

// ---------------- LayerNorm (bias + residual folded in; Yb is bf16) ----------------
__global__ __launch_bounds__(256) void ln_kernel(const unsigned short* __restrict__ Yb,
                                                 const float* __restrict__ qres,
                                                 const float* __restrict__ bo,
                                                 const float* __restrict__ gamma,
                                                 const float* __restrict__ beta,
                                                 float* __restrict__ out) {
    int row = blockIdx.x;
    int t = threadIdx.x;
    ushortv4 yv = ((const ushortv4*)(Yb + (size_t)row * DMODEL))[t];
    floatv4 qv = ((const floatv4*)(qres + (size_t)row * DMODEL))[t];
    floatv4 bv = ((const floatv4*)bo)[t];
    floatv4 v;
    v.x = bf2f(yv.x) + bv.x + qv.x;
    v.y = bf2f(yv.y) + bv.y + qv.y;
    v.z = bf2f(yv.z) + bv.z + qv.z;
    v.w = bf2f(yv.w) + bv.w + qv.w;
    float s1 = v.x + v.y + v.z + v.w;
    float s2 = v.x * v.x + v.y * v.y + v.z * v.z + v.w * v.w;
#pragma unroll
    for (int m = 1; m < 64; m <<= 1) { s1 += __shfl_xor(s1, m); s2 += __shfl_xor(s2, m); }
    __shared__ float red[8];
    int w = t >> 6, lane = t & 63;
    if (lane == 0) { red[w] = s1; red[4 + w] = s2; }
    __syncthreads();
    s1 = red[0] + red[1] + red[2] + red[3];
    s2 = red[4] + red[5] + red[6] + red[7];
    float mu = s1 * (1.0f / DMODEL);
    float var = s2 * (1.0f / DMODEL) - mu * mu;
    float rstd = rsqrtf(var + 1e-5f);
    floatv4 g = ((const floatv4*)gamma)[t];
    floatv4 bb = ((const floatv4*)beta)[t];
    floatv4 o;
    o.x = (v.x - mu) * rstd * g.x + bb.x;
    o.y = (v.y - mu) * rstd * g.y + bb.y;
    o.z = (v.z - mu) * rstd * g.z + bb.z;
    o.w = (v.w - mu) * rstd * g.w + bb.w;
    ((floatv4*)(out + (size_t)row * DMODEL))[t] = o;
}

// ---------------- launch ----------------
extern "C" void kernel_launch(void* const* d_in, const int* in_sizes, int n_in,
                              void* d_out, int out_size, void* d_ws, size_t ws_size,
                              hipStream_t stream) {
    const float* q = (const float*)d_in[0];
    const float* k = (const float*)d_in[1];
    const float* v = (const float*)d_in[2];
    const int* mask = (const int*)d_in[3];
    const float* Wq = (const float*)d_in[4];
    const float* Wk = (const float*)d_in[5];
    const float* Wv = (const float*)d_in[6];
    const float* Wo = (const float*)d_in[7];
    const float* bo = (const float*)d_in[8];
    const float* gamma = (const float*)d_in[9];
    const float* beta = (const float*)d_in[10];

    float* out = (float*)d_out;
    float* attn = out + (size_t)BB * SS * DMODEL;

    const size_t NTOK = (size_t)BB * SS;          // 4096
    unsigned short* qb = (unsigned short*)d_ws;   // [4096][1024] bf16
    unsigned short* kb = qb + NTOK * DMODEL;
    unsigned short* vb = kb + NTOK * DMODEL;
    unsigned short* Wqt = vb + NTOK * DMODEL;     // [1024][1024] bf16 (transposed)
    unsigned short* Wkt = Wqt + (size_t)DMODEL * DMODEL;
    unsigned short* Wvt = Wkt + (size_t)DMODEL * DMODEL;
    unsigned short* Wot = Wvt + (size_t)DMODEL * DMODEL;
    unsigned short* Qp = Wot + (size_t)DMODEL * DMODEL;  // [B,H,S,64] bf16 (pre-scaled)
    unsigned short* Kp = Qp + NTOK * DMODEL;
    unsigned short* Vt = Kp + NTOK * DMODEL;      // [B,H,64,S] bf16 (transposed)
    unsigned short* Ob = Vt + NTOK * DMODEL;      // [4096][1024] bf16
    unsigned short* Yb = qb;                      // reuse qb region post-attention (bf16)

    prep<<<16384, 256, 0, stream>>>(q, k, v, qb, kb, vb, Wq, Wk, Wv, Wo,
                                    Wqt, Wkt, Wvt, Wot);

    gemm_qkv<<<dim3(24, 32), 256, 0, stream>>>(qb, kb, vb, Wqt, Wkt, Wvt, Qp, Kp, Vt);

    attn_fused<<<512, 256, 0, stream>>>(Qp, Kp, Vt, mask, attn, Ob);

    gemm_out<<<dim3(8, 32), 256, 0, stream>>>(Ob, Wot, Yb);

    ln_kernel<<<(int)NTOK, 256, 0, stream>>>(Yb, q, bo, gamma, beta, out);
}

// Round 15
// 247.738 us; speedup vs baseline: 1.4123x; 1.1183x over previous
//
#include <hip/hip_runtime.h>
#include <stdint.h>
#include <stddef.h>

#define NHEAD 16
#define DMODEL 1024
#define SS 2048
#define BB 2

typedef __attribute__((ext_vector_type(8))) short bf16x8;
typedef __attribute__((ext_vector_type(4))) float f32x4;
typedef __attribute__((ext_vector_type(4))) float floatv4;
typedef __attribute__((ext_vector_type(4))) unsigned short ushortv4;
typedef __attribute__((ext_vector_type(8))) unsigned short ushortv8;

#define MFMA16(A, B, C) __builtin_amdgcn_mfma_f32_16x16x32_bf16(A, B, C, 0, 0, 0)

__device__ __forceinline__ unsigned short f2bf(float f) {
    union { float f; unsigned u; } x;
    x.f = f;
    unsigned r = x.u + 0x7FFFu + ((x.u >> 16) & 1u);  // RNE
    return (unsigned short)(r >> 16);
}

__device__ __forceinline__ unsigned short f2bf_trunc(float f) {
    union { float f; unsigned u; } x;
    x.f = f;
    return (unsigned short)(x.u >> 16);
}

__device__ __forceinline__ float bf2f(unsigned short u) {
    union { unsigned u; float f; } x;
    x.u = ((unsigned)u) << 16;
    return x.f;
}

// ---------------- prep: cvt3 + wtrans4 merged into one launch ----------------
__global__ __launch_bounds__(256) void prep(
    const float* __restrict__ q, const float* __restrict__ k, const float* __restrict__ v,
    unsigned short* __restrict__ qb, unsigned short* __restrict__ kb,
    unsigned short* __restrict__ vb,
    const float* __restrict__ W0, const float* __restrict__ W1,
    const float* __restrict__ W2, const float* __restrict__ W3,
    unsigned short* __restrict__ T0, unsigned short* __restrict__ T1,
    unsigned short* __restrict__ T2, unsigned short* __restrict__ T3) {
    __shared__ float tile[32][33];
    int blk = blockIdx.x;
    if (blk < 12288) {
        int which = blk >> 12;
        int i = (blk & 4095) * 256 + threadIdx.x;
        const float* src = which == 0 ? q : (which == 1 ? k : v);
        unsigned short* dst = which == 0 ? qb : (which == 1 ? kb : vb);
        floatv4 x = ((const floatv4*)src)[i];
        ushortv4 o;
        o.x = f2bf(x.x); o.y = f2bf(x.y); o.z = f2bf(x.z); o.w = f2bf(x.w);
        ((ushortv4*)dst)[i] = o;
    } else {
        int t = blk - 12288;
        int sel = t >> 10;
        int rest = t & 1023;
        const float* W = sel == 0 ? W0 : (sel == 1 ? W1 : (sel == 2 ? W2 : W3));
        unsigned short* Wt = sel == 0 ? T0 : (sel == 1 ? T1 : (sel == 2 ? T2 : T3));
        float scl = (sel == 0) ? 0.03125f : 1.0f;
        int tx = threadIdx.x & 31, ty = threadIdx.x >> 5;
        int nb = (rest & 31) * 32, kb2 = (rest >> 5) * 32;
#pragma unroll
        for (int i = 0; i < 4; i++)
            tile[ty + i * 8][tx] = W[(size_t)(kb2 + ty + i * 8) * DMODEL + nb + tx];
        __syncthreads();
#pragma unroll
        for (int i = 0; i < 4; i++)
            Wt[(size_t)(nb + ty + i * 8) * DMODEL + kb2 + tx] =
                f2bf(tile[tx][ty + i * 8] * scl);
    }
}

// ---------------- GEMM core: 128x128 tile, BK=64, 4 waves, swizzled LDS ----------------
__device__ __forceinline__ void stage_tile_sw(const unsigned short* __restrict__ src, int ld,
                                              unsigned short* lds) {
    int t = threadIdx.x;
#pragma unroll
    for (int i = 0; i < 4; i++) {
        int pos = i * 256 + t;            // 16B granule index
        int row = pos >> 3;
        int g = pos & 7;
        int kcol = (g ^ (row & 7)) * 8;   // inverse-swizzled source column
        __builtin_amdgcn_global_load_lds(
            (__attribute__((address_space(1))) void*)(src + row * ld + kcol),
            (__attribute__((address_space(3))) void*)(lds + pos * 8), 16, 0, 0);
    }
}

__device__ __forceinline__ bf16x8 frag_ld(const unsigned short* lds, int row, int koff) {
    int idx = row * 64 + (koff ^ ((row & 7) << 3));
    return *(const bf16x8*)(lds + idx);
}

__device__ __forceinline__ void gemm_core(const unsigned short* __restrict__ A,
                                          const unsigned short* __restrict__ Bt,
                                          int mbase, int nbase,
                                          unsigned short* As, unsigned short* Bs,
                                          f32x4 acc[4][4]) {
    int tid = threadIdx.x;
    int w = tid >> 6, lane = tid & 63, lg = lane >> 4, li = lane & 15;
    int wm = w >> 1, wn = w & 1;
#pragma unroll
    for (int mi = 0; mi < 4; mi++)
#pragma unroll
        for (int ni = 0; ni < 4; ni++) acc[mi][ni] = f32x4{0.f, 0.f, 0.f, 0.f};

    for (int ks = 0; ks < DMODEL / 64; ks++) {
        __syncthreads();
        stage_tile_sw(A + (size_t)mbase * DMODEL + ks * 64, DMODEL, As);
        stage_tile_sw(Bt + (size_t)nbase * DMODEL + ks * 64, DMODEL, Bs);
        __syncthreads();
        bf16x8 af[2][4], bfr[2][4];
#pragma unroll
        for (int kc = 0; kc < 2; kc++) {
#pragma unroll
            for (int mi = 0; mi < 4; mi++)
                af[kc][mi] = frag_ld(As, wm * 64 + mi * 16 + li, kc * 32 + lg * 8);
#pragma unroll
            for (int ni = 0; ni < 4; ni++)
                bfr[kc][ni] = frag_ld(Bs, wn * 64 + ni * 16 + li, kc * 32 + lg * 8);
        }
#pragma unroll
        for (int kc = 0; kc < 2; kc++)
#pragma unroll
            for (int mi = 0; mi < 4; mi++)
#pragma unroll
                for (int ni = 0; ni < 4; ni++)
                    acc[mi][ni] = MFMA16(af[kc][mi], bfr[kc][ni], acc[mi][ni]);
    }
}

#define CS_STRIDE 136  // 128 + 8 u16 pad

// ---------------- fused QKV projection; coalesced epilogue via LDS transpose ----------------
__global__ __launch_bounds__(256) void gemm_qkv(
    const unsigned short* __restrict__ qb, const unsigned short* __restrict__ kbuf,
    const unsigned short* __restrict__ vb,
    const unsigned short* __restrict__ Wqt, const unsigned short* __restrict__ Wkt,
    const unsigned short* __restrict__ Wvt,
    unsigned short* __restrict__ Qp, unsigned short* __restrict__ Kp,
    unsigned short* __restrict__ Vt) {
    __shared__ unsigned short LDSbuf[128 * CS_STRIDE];
    unsigned short* As = LDSbuf;
    unsigned short* Bs = LDSbuf + 128 * 64;
    unsigned short* Cs = LDSbuf;

    int bid = blockIdx.y * 24 + blockIdx.x;       // bijective XCD swizzle, nwg=768
    int nl = (bid & 7) * 96 + (bid >> 3);
    int nt = nl % 24;
    int mbase = (nl / 24) * 128;
    int seg = nt >> 3;
    int nbase = (nt & 7) * 128;
    const unsigned short* A = seg == 0 ? qb : (seg == 1 ? kbuf : vb);
    const unsigned short* Bt = seg == 0 ? Wqt : (seg == 1 ? Wkt : Wvt);

    f32x4 acc[4][4];
    gemm_core(A, Bt, mbase, nbase, As, Bs, acc);

    int tid = threadIdx.x, w = tid >> 6, lane = tid & 63, lg = lane >> 4, li = lane & 15;
    int wm = w >> 1, wn = w & 1;

    __syncthreads();
    if (seg == 2) {
#pragma unroll
        for (int mi = 0; mi < 4; mi++)
#pragma unroll
            for (int ni = 0; ni < 4; ni++) {
                int nloc = wn * 64 + ni * 16 + li;
                int mloc = wm * 64 + mi * 16 + lg * 4;
#pragma unroll
                for (int r = 0; r < 4; r++)
                    Cs[nloc * CS_STRIDE + mloc + r] = f2bf(acc[mi][ni][r]);
            }
        __syncthreads();
#pragma unroll
        for (int i = 0; i < 8; i++) {
            int g = i * 256 + tid;
            int nloc = g >> 4, mo = (g & 15) * 8;
            int ng = nbase + nloc, h = ng >> 6, d = ng & 63;
            int m0 = mbase + mo, b = m0 >> 11, s0 = m0 & 2047;
            *(ushortv8*)(Vt + (((size_t)((b * NHEAD + h) * 64 + d)) << 11) + s0) =
                *(const ushortv8*)(Cs + nloc * CS_STRIDE + mo);
        }
    } else {
        unsigned short* Out = seg == 0 ? Qp : Kp;
#pragma unroll
        for (int mi = 0; mi < 4; mi++)
#pragma unroll
            for (int ni = 0; ni < 4; ni++) {
                int nloc = wn * 64 + ni * 16 + li;
                int mloc = wm * 64 + mi * 16 + lg * 4;
#pragma unroll
                for (int r = 0; r < 4; r++)
                    Cs[(mloc + r) * CS_STRIDE + nloc] = f2bf(acc[mi][ni][r]);
            }
        __syncthreads();
#pragma unroll
        for (int i = 0; i < 8; i++) {
            int g = i * 256 + tid;
            int row = g >> 4, on = (g & 15) * 8;
            int ng = nbase + on, h = ng >> 6, d = ng & 63;
            int m0 = mbase + row, b = m0 >> 11, s0 = m0 & 2047;
            *(ushortv8*)(Out + ((size_t)((b * NHEAD + h) * SS + s0)) * 64 + d) =
                *(const ushortv8*)(Cs + row * CS_STRIDE + on);
        }
    }
}

// ---------------- output projection -> Yb bf16 (bias/residual folded into LN) ----------------
__global__ __launch_bounds__(256) void gemm_out(
    const unsigned short* __restrict__ Ob, const unsigned short* __restrict__ Wot,
    unsigned short* __restrict__ Yb) {
    __shared__ unsigned short LDSbuf[128 * CS_STRIDE];
    unsigned short* As = LDSbuf;
    unsigned short* Bs = LDSbuf + 128 * 64;
    unsigned short* Cs = LDSbuf;

    int bid = blockIdx.y * 8 + blockIdx.x;
    int nl = (bid & 7) * 32 + (bid >> 3);   // nwg=256
    int nbase = (nl % 8) * 128;
    int mbase = (nl / 8) * 128;

    f32x4 acc[4][4];
    gemm_core(Ob, Wot, mbase, nbase, As, Bs, acc);

    int tid = threadIdx.x, w = tid >> 6, lane = tid & 63, lg = lane >> 4, li = lane & 15;
    int wm = w >> 1, wn = w & 1;

    __syncthreads();
#pragma unroll
    for (int mi = 0; mi < 4; mi++)
#pragma unroll
        for (int ni = 0; ni < 4; ni++) {
            int nloc = wn * 64 + ni * 16 + li;
            int mloc = wm * 64 + mi * 16 + lg * 4;
#pragma unroll
            for (int r = 0; r < 4; r++)
                Cs[(mloc + r) * CS_STRIDE + nloc] = f2bf(acc[mi][ni][r]);
        }
    __syncthreads();
#pragma unroll
    for (int i = 0; i < 8; i++) {
        int g = i * 256 + tid;
        int row = g >> 4, on = (g & 15) * 8;
        *(ushortv8*)(Yb + (size_t)(mbase + row) * DMODEL + nbase + on) =
            *(const ushortv8*)(Cs + row * CS_STRIDE + on);
    }
}

// ---------------- fused attention (R14 + pipelined pass-B stores, nt) ----------------
// grid 512 (XCD-bijective): 16 q-tiles(128) x 32 bh. 4 waves x (2 x 16) q-rows.
// Pass A: K/V dbuf via global_load_lds, f32 mask bias, no stores in loop.
// Pass B: per-wave Pt DOUBLE buffer — compute tile t into Pt[t&1] while the
// coalesced (4 rows x 256B) NONTEMPORAL stores of tile t-1 drain from Pt[~t&1].
__device__ __forceinline__ void stage_kv(const unsigned short* __restrict__ Kb,
                                         const unsigned short* __restrict__ Vtb, int s0,
                                         unsigned short* kl, unsigned short* vl, int tid) {
#pragma unroll
    for (int i = 0; i < 2; i++) {
        int pos = i * 256 + tid;          // 16B granule index, 512 = 64 rows x 8
        int row = pos >> 3, g = pos & 7;
        int col = (g ^ (row & 7)) * 8;    // inverse-swizzled source column
        __builtin_amdgcn_global_load_lds(
            (__attribute__((address_space(1))) void*)(Kb + (size_t)(s0 + row) * 64 + col),
            (__attribute__((address_space(3))) void*)(kl + pos * 8), 16, 0, 0);
    }
#pragma unroll
    for (int i = 0; i < 2; i++) {
        int pos = i * 256 + tid;
        int row = pos >> 3, g = pos & 7;
        int col = (g ^ (row & 7)) * 8;
        __builtin_amdgcn_global_load_lds(
            (__attribute__((address_space(1))) void*)(Vtb + (size_t)row * SS + s0 + col),
            (__attribute__((address_space(3))) void*)(vl + pos * 8), 16, 0, 0);
    }
}

__global__ __launch_bounds__(256, 2) void attn_fused(
    const unsigned short* __restrict__ Qp, const unsigned short* __restrict__ Kp,
    const unsigned short* __restrict__ Vt, const int* __restrict__ mask,
    float* __restrict__ attn_out, unsigned short* __restrict__ Ob) {
    // 72KB: [0,48K) KsB/VsB/PlB (pass A) overlaid by Pt dbuf 64KB (pass B);
    // Ml lives at [64K,72K) and survives both passes.
    __shared__ __align__(16) unsigned short SH[36864];
    unsigned short* KsB = SH;                  // [2][64*64]   (16KB)
    unsigned short* VsB = SH + 8192;           // [2][64*64]   (16KB)
    unsigned short* PlB = SH + 16384;          // [4][32*64]   (16KB)
    float* Ml = (float*)(SH + 32768);          // [2048]       (8KB at byte 64K)

    int blk = blockIdx.x;
    int xslot = blk & 7, rest = blk >> 3;
    int qt = rest & 15, bg = rest >> 4;
    int bh = bg * 8 + xslot, b = bh >> 4;
    int q0 = qt * 128;
    int tid = threadIdx.x, w = tid >> 6, lane = tid & 63, lg = lane >> 4, li = lane & 15;
    const unsigned short* Qb = Qp + (size_t)bh * SS * 64;
    const unsigned short* Kb = Kp + (size_t)bh * SS * 64;
    const unsigned short* Vtb = Vt + (size_t)bh * 64 * SS;
    const int* mb = mask + b * SS;
    int qw = q0 + w * 32;
    int sw = (li & 7) << 3;

    stage_kv(Kb, Vtb, 0, KsB, VsB, tid);

#pragma unroll
    for (int i = 0; i < SS / 256; i++) {
        int idx = i * 256 + tid;
        Ml[idx] = mb[idx] ? 0.f : -1e10f;
    }

    bf16x8 qa[2][2];
#pragma unroll
    for (int fq = 0; fq < 2; fq++) {
        int q = qw + fq * 16 + li;
        qa[fq][0] = *(const bf16x8*)(Qb + (size_t)q * 64 + lg * 8);
        qa[fq][1] = *(const bf16x8*)(Qb + (size_t)q * 64 + 32 + lg * 8);
    }

    f32x4 oacc[2][4];
#pragma unroll
    for (int fq = 0; fq < 2; fq++)
#pragma unroll
        for (int gd = 0; gd < 4; gd++) oacc[fq][gd] = f32x4{0.f, 0.f, 0.f, 0.f};
    float lsA[2] = {0.f, 0.f}, lsB[2] = {0.f, 0.f};
    unsigned short* Pw = PlB + w * (32 * 64);

    asm volatile("s_waitcnt vmcnt(0) lgkmcnt(0)" ::: "memory");
    __builtin_amdgcn_s_barrier();

#pragma unroll 1
    for (int t = 0; t < 32; t++) {
        int k0 = t * 64;
        if (t + 1 < 32)
            stage_kv(Kb, Vtb, k0 + 64, KsB + ((t + 1) & 1) * 4096,
                     VsB + ((t + 1) & 1) * 4096, tid);
        __builtin_amdgcn_sched_barrier(0);
        const unsigned short* Kc = KsB + (t & 1) * 4096;
        const unsigned short* Vc = VsB + (t & 1) * 4096;
#pragma unroll
        for (int fk = 0; fk < 4; fk++) {
            int row = fk * 16 + li;
            bf16x8 kf0 = *(const bf16x8*)(Kc + row * 64 + ((lg * 8) ^ sw));
            bf16x8 kf1 = *(const bf16x8*)(Kc + row * 64 + ((32 + lg * 8) ^ sw));
            floatv4 mk = *(const floatv4*)(Ml + k0 + fk * 16 + lg * 4);
#pragma unroll
            for (int fq = 0; fq < 2; fq++) {
                f32x4 sc = f32x4{0.f, 0.f, 0.f, 0.f};
                sc = MFMA16(kf0, qa[fq][0], sc);
                sc = MFMA16(kf1, qa[fq][1], sc);
                floatv4 pv;
#pragma unroll
                for (int r = 0; r < 4; r++)
                    pv[r] = __expf(fminf(sc[r] + mk[r], 80.f));
                lsA[fq] += pv[0] + pv[1];
                lsB[fq] += pv[2] + pv[3];
                ushortv4 pk;
#pragma unroll
                for (int r = 0; r < 4; r++) pk[r] = f2bf_trunc(pv[r]);
                *(ushortv4*)(Pw + (fq * 16 + li) * 64 + ((fk * 16 + lg * 4) ^ sw)) = pk;
            }
        }
        // PV: vf reads shared across both fq sub-tiles
#pragma unroll
        for (int kc = 0; kc < 2; kc++) {
            bf16x8 vf[4];
#pragma unroll
            for (int gd = 0; gd < 4; gd++) {
                int vrow = gd * 16 + li;
                vf[gd] = *(const bf16x8*)(Vc + vrow * 64 + ((kc * 32 + lg * 8) ^ sw));
            }
#pragma unroll
            for (int fq = 0; fq < 2; fq++) {
                bf16x8 pa = *(const bf16x8*)(Pw + (fq * 16 + li) * 64 +
                                             ((kc * 32 + lg * 8) ^ sw));
#pragma unroll
                for (int gd = 0; gd < 4; gd++)
                    oacc[fq][gd] = MFMA16(pa, vf[gd], oacc[fq][gd]);
            }
        }
        asm volatile("s_waitcnt vmcnt(0)" ::: "memory");
        __builtin_amdgcn_s_barrier();
    }

    // linv per (fq, li); broadcast to D-layout rows via per-wave LDS
    float linvv[2];
    float* LinvW = (float*)Pw;  // Pl[w] dead now
#pragma unroll
    for (int fq = 0; fq < 2; fq++) {
        float lsum = lsA[fq] + lsB[fq];
        lsum += __shfl_xor(lsum, 16);
        lsum += __shfl_xor(lsum, 32);
        linvv[fq] = 1.0f / lsum;
        if (lg == 0) LinvW[fq * 16 + li] = linvv[fq];
    }
    int h = bh & 15;
#pragma unroll
    for (int fq = 0; fq < 2; fq++)
#pragma unroll
        for (int gd = 0; gd < 4; gd++)
#pragma unroll
            for (int r = 0; r < 4; r++) {
                int srow = qw + fq * 16 + lg * 4 + r;
                float o = oacc[fq][gd][r] * LinvW[fq * 16 + lg * 4 + r];
                Ob[(size_t)(b * SS + srow) * DMODEL + h * 64 + gd * 16 + li] = f2bf(o);
            }

    // ---- pass B: pipelined compute/store via per-wave Pt double buffer ----
    __builtin_amdgcn_s_barrier();  // all waves done with PlB (LinvW) + Ks/Vs
    float* PtW = (float*)SH + w * 4096;   // 2 x 2048 f32 per wave (16KB)
    int rgrp = lane >> 4;
    float* arowbase = attn_out + ((size_t)bh * SS + qw) * SS;

#pragma unroll 1
    for (int t = 0; t < 32; t++) {
        int k0 = t * 64;
        float* Pt = PtW + (t & 1) * 2048;
        // compute tile t -> Pt[t&1]
#pragma unroll
        for (int fk = 0; fk < 4; fk++) {
            const unsigned short* kp = Kb + (size_t)(k0 + fk * 16 + li) * 64;
            bf16x8 kf0 = *(const bf16x8*)(kp + lg * 8);
            bf16x8 kf1 = *(const bf16x8*)(kp + 32 + lg * 8);
            floatv4 mk = *(const floatv4*)(Ml + k0 + fk * 16 + lg * 4);
#pragma unroll
            for (int fq = 0; fq < 2; fq++) {
                f32x4 sc = f32x4{0.f, 0.f, 0.f, 0.f};
                sc = MFMA16(kf0, qa[fq][0], sc);
                sc = MFMA16(kf1, qa[fq][1], sc);
                floatv4 pv;
#pragma unroll
                for (int r = 0; r < 4; r++)
                    pv[r] = __expf(fminf(sc[r] + mk[r], 80.f)) * linvv[fq];
                int prow = fq * 16 + li;
                *(floatv4*)(Pt + prow * 64 + ((fk * 16 + lg * 4) ^ ((prow & 7) << 3))) = pv;
            }
        }
        // store tile t-1 from the other buffer (coalesced 4 rows x 256B, nontemporal)
        if (t > 0) {
            float* Pp = PtW + ((t & 1) ^ 1) * 2048;
            int pk0 = k0 - 64;
#pragma unroll
            for (int g = 0; g < 8; g++) {
                int row = g * 4 + rgrp;
                int colb = li * 4;
                floatv4 vv = *(const floatv4*)(Pp + row * 64 + (colb ^ ((row & 7) << 3)));
                __builtin_nontemporal_store(
                    vv, (floatv4*)(arowbase + (size_t)row * SS + pk0 + colb));
            }
        }
    }
    // epilogue: store tile 31
    {
        float* Pp = PtW + 2048;  // (31&1)=1
        int pk0 = 31 * 64;
#pragma unroll
        for (int g = 0; g < 8; g++) {
            int row = g * 4 + rgrp;
            int colb = li * 4;
            floatv4 vv = *(const floatv4*)(Pp + row * 64 + (colb ^ ((row & 7) << 3)));
            __builtin_nontemporal_store(
                vv, (floatv4*)(arowbase + (size_t)row * SS + pk0 + colb));
        }
    }
}

// ---------------- LayerNorm (bias + residual folded in; Yb is bf16) ----------------
__global__ __launch_bounds__(256) void ln_kernel(const unsigned short* __restrict__ Yb,
                                                 const float* __restrict__ qres,
                                                 const float* __restrict__ bo,
                                                 const float* __restrict__ gamma,
                                                 const float* __restrict__ beta,
                                                 float* __restrict__ out) {
    int row = blockIdx.x;
    int t = threadIdx.x;
    ushortv4 yv = ((const ushortv4*)(Yb + (size_t)row * DMODEL))[t];
    floatv4 qv = ((const floatv4*)(qres + (size_t)row * DMODEL))[t];
    floatv4 bv = ((const floatv4*)bo)[t];
    floatv4 v;
    v.x = bf2f(yv.x) + bv.x + qv.x;
    v.y = bf2f(yv.y) + bv.y + qv.y;
    v.z = bf2f(yv.z) + bv.z + qv.z;
    v.w = bf2f(yv.w) + bv.w + qv.w;
    float s1 = v.x + v.y + v.z + v.w;
    float s2 = v.x * v.x + v.y * v.y + v.z * v.z + v.w * v.w;
#pragma unroll
    for (int m = 1; m < 64; m <<= 1) { s1 += __shfl_xor(s1, m); s2 += __shfl_xor(s2, m); }
    __shared__ float red[8];
    int w = t >> 6, lane = t & 63;
    if (lane == 0) { red[w] = s1; red[4 + w] = s2; }
    __syncthreads();
    s1 = red[0] + red[1] + red[2] + red[3];
    s2 = red[4] + red[5] + red[6] + red[7];
    float mu = s1 * (1.0f / DMODEL);
    float var = s2 * (1.0f / DMODEL) - mu * mu;
    float rstd = rsqrtf(var + 1e-5f);
    floatv4 g = ((const floatv4*)gamma)[t];
    floatv4 bb = ((const floatv4*)beta)[t];
    floatv4 o;
    o.x = (v.x - mu) * rstd * g.x + bb.x;
    o.y = (v.y - mu) * rstd * g.y + bb.y;
    o.z = (v.z - mu) * rstd * g.z + bb.z;
    o.w = (v.w - mu) * rstd * g.w + bb.w;
    ((floatv4*)(out + (size_t)row * DMODEL))[t] = o;
}

// ---------------- launch ----------------
extern "C" void kernel_launch(void* const* d_in, const int* in_sizes, int n_in,
                              void* d_out, int out_size, void* d_ws, size_t ws_size,
                              hipStream_t stream) {
    const float* q = (const float*)d_in[0];
    const float* k = (const float*)d_in[1];
    const float* v = (const float*)d_in[2];
    const int* mask = (const int*)d_in[3];
    const float* Wq = (const float*)d_in[4];
    const float* Wk = (const float*)d_in[5];
    const float* Wv = (const float*)d_in[6];
    const float* Wo = (const float*)d_in[7];
    const float* bo = (const float*)d_in[8];
    const float* gamma = (const float*)d_in[9];
    const float* beta = (const float*)d_in[10];

    float* out = (float*)d_out;
    float* attn = out + (size_t)BB * SS * DMODEL;

    const size_t NTOK = (size_t)BB * SS;          // 4096
    unsigned short* qb = (unsigned short*)d_ws;   // [4096][1024] bf16
    unsigned short* kb = qb + NTOK * DMODEL;
    unsigned short* vb = kb + NTOK * DMODEL;
    unsigned short* Wqt = vb + NTOK * DMODEL;     // [1024][1024] bf16 (transposed)
    unsigned short* Wkt = Wqt + (size_t)DMODEL * DMODEL;
    unsigned short* Wvt = Wkt + (size_t)DMODEL * DMODEL;
    unsigned short* Wot = Wvt + (size_t)DMODEL * DMODEL;
    unsigned short* Qp = Wot + (size_t)DMODEL * DMODEL;  // [B,H,S,64] bf16 (pre-scaled)
    unsigned short* Kp = Qp + NTOK * DMODEL;
    unsigned short* Vt = Kp + NTOK * DMODEL;      // [B,H,64,S] bf16 (transposed)
    unsigned short* Ob = Vt + NTOK * DMODEL;      // [4096][1024] bf16
    unsigned short* Yb = qb;                      // reuse qb region post-attention (bf16)

    prep<<<16384, 256, 0, stream>>>(q, k, v, qb, kb, vb, Wq, Wk, Wv, Wo,
                                    Wqt, Wkt, Wvt, Wot);

    gemm_qkv<<<dim3(24, 32), 256, 0, stream>>>(qb, kb, vb, Wqt, Wkt, Wvt, Qp, Kp, Vt);

    attn_fused<<<512, 256, 0, stream>>>(Qp, Kp, Vt, mask, attn, Ob);

    gemm_out<<<dim3(8, 32), 256, 0, stream>>>(Ob, Wot, Yb);

    ln_kernel<<<(int)NTOK, 256, 0, stream>>>(Yb, q, bo, gamma, beta, out);
}

// Round 16
// 246.480 us; speedup vs baseline: 1.4195x; 1.0051x over previous
//
#include <hip/hip_runtime.h>
#include <stdint.h>
#include <stddef.h>

#define NHEAD 16
#define DMODEL 1024
#define SS 2048
#define BB 2

typedef __attribute__((ext_vector_type(8))) short bf16x8;
typedef __attribute__((ext_vector_type(4))) float f32x4;
typedef __attribute__((ext_vector_type(4))) float floatv4;
typedef __attribute__((ext_vector_type(4))) unsigned short ushortv4;
typedef __attribute__((ext_vector_type(8))) unsigned short ushortv8;

#define MFMA16(A, B, C) __builtin_amdgcn_mfma_f32_16x16x32_bf16(A, B, C, 0, 0, 0)

__device__ __forceinline__ unsigned short f2bf(float f) {
    union { float f; unsigned u; } x;
    x.f = f;
    unsigned r = x.u + 0x7FFFu + ((x.u >> 16) & 1u);  // RNE
    return (unsigned short)(r >> 16);
}

__device__ __forceinline__ unsigned short f2bf_trunc(float f) {
    union { float f; unsigned u; } x;
    x.f = f;
    return (unsigned short)(x.u >> 16);
}

__device__ __forceinline__ float bf2f(unsigned short u) {
    union { unsigned u; float f; } x;
    x.u = ((unsigned)u) << 16;
    return x.f;
}

// ---------------- prep: cvt3 + wtrans4 merged into one launch ----------------
__global__ __launch_bounds__(256) void prep(
    const float* __restrict__ q, const float* __restrict__ k, const float* __restrict__ v,
    unsigned short* __restrict__ qb, unsigned short* __restrict__ kb,
    unsigned short* __restrict__ vb,
    const float* __restrict__ W0, const float* __restrict__ W1,
    const float* __restrict__ W2, const float* __restrict__ W3,
    unsigned short* __restrict__ T0, unsigned short* __restrict__ T1,
    unsigned short* __restrict__ T2, unsigned short* __restrict__ T3) {
    __shared__ float tile[32][33];
    int blk = blockIdx.x;
    if (blk < 12288) {
        int which = blk >> 12;
        int i = (blk & 4095) * 256 + threadIdx.x;
        const float* src = which == 0 ? q : (which == 1 ? k : v);
        unsigned short* dst = which == 0 ? qb : (which == 1 ? kb : vb);
        floatv4 x = ((const floatv4*)src)[i];
        ushortv4 o;
        o.x = f2bf(x.x); o.y = f2bf(x.y); o.z = f2bf(x.z); o.w = f2bf(x.w);
        ((ushortv4*)dst)[i] = o;
    } else {
        int t = blk - 12288;
        int sel = t >> 10;
        int rest = t & 1023;
        const float* W = sel == 0 ? W0 : (sel == 1 ? W1 : (sel == 2 ? W2 : W3));
        unsigned short* Wt = sel == 0 ? T0 : (sel == 1 ? T1 : (sel == 2 ? T2 : T3));
        float scl = (sel == 0) ? 0.03125f : 1.0f;
        int tx = threadIdx.x & 31, ty = threadIdx.x >> 5;
        int nb = (rest & 31) * 32, kb2 = (rest >> 5) * 32;
#pragma unroll
        for (int i = 0; i < 4; i++)
            tile[ty + i * 8][tx] = W[(size_t)(kb2 + ty + i * 8) * DMODEL + nb + tx];
        __syncthreads();
#pragma unroll
        for (int i = 0; i < 4; i++)
            Wt[(size_t)(nb + ty + i * 8) * DMODEL + kb2 + tx] =
                f2bf(tile[tx][ty + i * 8] * scl);
    }
}

// ---------------- GEMM core: 128x128 tile, BK=64, 4 waves, swizzled LDS ----------------
__device__ __forceinline__ void stage_tile_sw(const unsigned short* __restrict__ src, int ld,
                                              unsigned short* lds) {
    int t = threadIdx.x;
#pragma unroll
    for (int i = 0; i < 4; i++) {
        int pos = i * 256 + t;            // 16B granule index
        int row = pos >> 3;
        int g = pos & 7;
        int kcol = (g ^ (row & 7)) * 8;   // inverse-swizzled source column
        __builtin_amdgcn_global_load_lds(
            (__attribute__((address_space(1))) void*)(src + row * ld + kcol),
            (__attribute__((address_space(3))) void*)(lds + pos * 8), 16, 0, 0);
    }
}

__device__ __forceinline__ bf16x8 frag_ld(const unsigned short* lds, int row, int koff) {
    int idx = row * 64 + (koff ^ ((row & 7) << 3));
    return *(const bf16x8*)(lds + idx);
}

__device__ __forceinline__ void gemm_core(const unsigned short* __restrict__ A,
                                          const unsigned short* __restrict__ Bt,
                                          int mbase, int nbase,
                                          unsigned short* As, unsigned short* Bs,
                                          f32x4 acc[4][4]) {
    int tid = threadIdx.x;
    int w = tid >> 6, lane = tid & 63, lg = lane >> 4, li = lane & 15;
    int wm = w >> 1, wn = w & 1;
#pragma unroll
    for (int mi = 0; mi < 4; mi++)
#pragma unroll
        for (int ni = 0; ni < 4; ni++) acc[mi][ni] = f32x4{0.f, 0.f, 0.f, 0.f};

    for (int ks = 0; ks < DMODEL / 64; ks++) {
        __syncthreads();
        stage_tile_sw(A + (size_t)mbase * DMODEL + ks * 64, DMODEL, As);
        stage_tile_sw(Bt + (size_t)nbase * DMODEL + ks * 64, DMODEL, Bs);
        __syncthreads();
        bf16x8 af[2][4], bfr[2][4];
#pragma unroll
        for (int kc = 0; kc < 2; kc++) {
#pragma unroll
            for (int mi = 0; mi < 4; mi++)
                af[kc][mi] = frag_ld(As, wm * 64 + mi * 16 + li, kc * 32 + lg * 8);
#pragma unroll
            for (int ni = 0; ni < 4; ni++)
                bfr[kc][ni] = frag_ld(Bs, wn * 64 + ni * 16 + li, kc * 32 + lg * 8);
        }
#pragma unroll
        for (int kc = 0; kc < 2; kc++)
#pragma unroll
            for (int mi = 0; mi < 4; mi++)
#pragma unroll
                for (int ni = 0; ni < 4; ni++)
                    acc[mi][ni] = MFMA16(af[kc][mi], bfr[kc][ni], acc[mi][ni]);
    }
}

#define CS_STRIDE 136  // 128 + 8 u16 pad

// ---------------- fused QKV projection; coalesced epilogue via LDS transpose ----------------
__global__ __launch_bounds__(256) void gemm_qkv(
    const unsigned short* __restrict__ qb, const unsigned short* __restrict__ kbuf,
    const unsigned short* __restrict__ vb,
    const unsigned short* __restrict__ Wqt, const unsigned short* __restrict__ Wkt,
    const unsigned short* __restrict__ Wvt,
    unsigned short* __restrict__ Qp, unsigned short* __restrict__ Kp,
    unsigned short* __restrict__ Vt) {
    __shared__ unsigned short LDSbuf[128 * CS_STRIDE];
    unsigned short* As = LDSbuf;
    unsigned short* Bs = LDSbuf + 128 * 64;
    unsigned short* Cs = LDSbuf;

    int bid = blockIdx.y * 24 + blockIdx.x;       // bijective XCD swizzle, nwg=768
    int nl = (bid & 7) * 96 + (bid >> 3);
    int nt = nl % 24;
    int mbase = (nl / 24) * 128;
    int seg = nt >> 3;
    int nbase = (nt & 7) * 128;
    const unsigned short* A = seg == 0 ? qb : (seg == 1 ? kbuf : vb);
    const unsigned short* Bt = seg == 0 ? Wqt : (seg == 1 ? Wkt : Wvt);

    f32x4 acc[4][4];
    gemm_core(A, Bt, mbase, nbase, As, Bs, acc);

    int tid = threadIdx.x, w = tid >> 6, lane = tid & 63, lg = lane >> 4, li = lane & 15;
    int wm = w >> 1, wn = w & 1;

    __syncthreads();
    if (seg == 2) {
#pragma unroll
        for (int mi = 0; mi < 4; mi++)
#pragma unroll
            for (int ni = 0; ni < 4; ni++) {
                int nloc = wn * 64 + ni * 16 + li;
                int mloc = wm * 64 + mi * 16 + lg * 4;
#pragma unroll
                for (int r = 0; r < 4; r++)
                    Cs[nloc * CS_STRIDE + mloc + r] = f2bf(acc[mi][ni][r]);
            }
        __syncthreads();
#pragma unroll
        for (int i = 0; i < 8; i++) {
            int g = i * 256 + tid;
            int nloc = g >> 4, mo = (g & 15) * 8;
            int ng = nbase + nloc, h = ng >> 6, d = ng & 63;
            int m0 = mbase + mo, b = m0 >> 11, s0 = m0 & 2047;
            *(ushortv8*)(Vt + (((size_t)((b * NHEAD + h) * 64 + d)) << 11) + s0) =
                *(const ushortv8*)(Cs + nloc * CS_STRIDE + mo);
        }
    } else {
        unsigned short* Out = seg == 0 ? Qp : Kp;
#pragma unroll
        for (int mi = 0; mi < 4; mi++)
#pragma unroll
            for (int ni = 0; ni < 4; ni++) {
                int nloc = wn * 64 + ni * 16 + li;
                int mloc = wm * 64 + mi * 16 + lg * 4;
#pragma unroll
                for (int r = 0; r < 4; r++)
                    Cs[(mloc + r) * CS_STRIDE + nloc] = f2bf(acc[mi][ni][r]);
            }
        __syncthreads();
#pragma unroll
        for (int i = 0; i < 8; i++) {
            int g = i * 256 + tid;
            int row = g >> 4, on = (g & 15) * 8;
            int ng = nbase + on, h = ng >> 6, d = ng & 63;
            int m0 = mbase + row, b = m0 >> 11, s0 = m0 & 2047;
            *(ushortv8*)(Out + ((size_t)((b * NHEAD + h) * SS + s0)) * 64 + d) =
                *(const ushortv8*)(Cs + row * CS_STRIDE + on);
        }
    }
}

// ---------------- output projection -> Yb bf16 (bias/residual folded into LN) ----------------
__global__ __launch_bounds__(256) void gemm_out(
    const unsigned short* __restrict__ Ob, const unsigned short* __restrict__ Wot,
    unsigned short* __restrict__ Yb) {
    __shared__ unsigned short LDSbuf[128 * CS_STRIDE];
    unsigned short* As = LDSbuf;
    unsigned short* Bs = LDSbuf + 128 * 64;
    unsigned short* Cs = LDSbuf;

    int bid = blockIdx.y * 8 + blockIdx.x;
    int nl = (bid & 7) * 32 + (bid >> 3);   // nwg=256
    int nbase = (nl % 8) * 128;
    int mbase = (nl / 8) * 128;

    f32x4 acc[4][4];
    gemm_core(Ob, Wot, mbase, nbase, As, Bs, acc);

    int tid = threadIdx.x, w = tid >> 6, lane = tid & 63, lg = lane >> 4, li = lane & 15;
    int wm = w >> 1, wn = w & 1;

    __syncthreads();
#pragma unroll
    for (int mi = 0; mi < 4; mi++)
#pragma unroll
        for (int ni = 0; ni < 4; ni++) {
            int nloc = wn * 64 + ni * 16 + li;
            int mloc = wm * 64 + mi * 16 + lg * 4;
#pragma unroll
            for (int r = 0; r < 4; r++)
                Cs[(mloc + r) * CS_STRIDE + nloc] = f2bf(acc[mi][ni][r]);
        }
    __syncthreads();
#pragma unroll
    for (int i = 0; i < 8; i++) {
        int g = i * 256 + tid;
        int row = g >> 4, on = (g & 15) * 8;
        *(ushortv8*)(Yb + (size_t)(mbase + row) * DMODEL + nbase + on) =
            *(const ushortv8*)(Cs + row * CS_STRIDE + on);
    }
}

// ---------------- fused attention (R15 + T5 setprio) ----------------
__device__ __forceinline__ void stage_kv(const unsigned short* __restrict__ Kb,
                                         const unsigned short* __restrict__ Vtb, int s0,
                                         unsigned short* kl, unsigned short* vl, int tid) {
#pragma unroll
    for (int i = 0; i < 2; i++) {
        int pos = i * 256 + tid;          // 16B granule index, 512 = 64 rows x 8
        int row = pos >> 3, g = pos & 7;
        int col = (g ^ (row & 7)) * 8;    // inverse-swizzled source column
        __builtin_amdgcn_global_load_lds(
            (__attribute__((address_space(1))) void*)(Kb + (size_t)(s0 + row) * 64 + col),
            (__attribute__((address_space(3))) void*)(kl + pos * 8), 16, 0, 0);
    }
#pragma unroll
    for (int i = 0; i < 2; i++) {
        int pos = i * 256 + tid;
        int row = pos >> 3, g = pos & 7;
        int col = (g ^ (row & 7)) * 8;
        __builtin_amdgcn_global_load_lds(
            (__attribute__((address_space(1))) void*)(Vtb + (size_t)row * SS + s0 + col),
            (__attribute__((address_space(3))) void*)(vl + pos * 8), 16, 0, 0);
    }
}

__global__ __launch_bounds__(256, 2) void attn_fused(
    const unsigned short* __restrict__ Qp, const unsigned short* __restrict__ Kp,
    const unsigned short* __restrict__ Vt, const int* __restrict__ mask,
    float* __restrict__ attn_out, unsigned short* __restrict__ Ob) {
    // 72KB: [0,64K) KsB/VsB/PlB (pass A) overlaid by Pt dbuf (pass B);
    // Ml at [64K,72K) survives both passes.
    __shared__ __align__(16) unsigned short SH[36864];
    unsigned short* KsB = SH;                  // [2][64*64]   (16KB)
    unsigned short* VsB = SH + 8192;           // [2][64*64]   (16KB)
    unsigned short* PlB = SH + 16384;          // [4][32*64]   (16KB)
    float* Ml = (float*)(SH + 32768);          // [2048]       (8KB at byte 64K)

    int blk = blockIdx.x;
    int xslot = blk & 7, rest = blk >> 3;
    int qt = rest & 15, bg = rest >> 4;
    int bh = bg * 8 + xslot, b = bh >> 4;
    int q0 = qt * 128;
    int tid = threadIdx.x, w = tid >> 6, lane = tid & 63, lg = lane >> 4, li = lane & 15;
    const unsigned short* Qb = Qp + (size_t)bh * SS * 64;
    const unsigned short* Kb = Kp + (size_t)bh * SS * 64;
    const unsigned short* Vtb = Vt + (size_t)bh * 64 * SS;
    const int* mb = mask + b * SS;
    int qw = q0 + w * 32;
    int sw = (li & 7) << 3;

    stage_kv(Kb, Vtb, 0, KsB, VsB, tid);

#pragma unroll
    for (int i = 0; i < SS / 256; i++) {
        int idx = i * 256 + tid;
        Ml[idx] = mb[idx] ? 0.f : -1e10f;
    }

    bf16x8 qa[2][2];
#pragma unroll
    for (int fq = 0; fq < 2; fq++) {
        int q = qw + fq * 16 + li;
        qa[fq][0] = *(const bf16x8*)(Qb + (size_t)q * 64 + lg * 8);
        qa[fq][1] = *(const bf16x8*)(Qb + (size_t)q * 64 + 32 + lg * 8);
    }

    f32x4 oacc[2][4];
#pragma unroll
    for (int fq = 0; fq < 2; fq++)
#pragma unroll
        for (int gd = 0; gd < 4; gd++) oacc[fq][gd] = f32x4{0.f, 0.f, 0.f, 0.f};
    float lsA[2] = {0.f, 0.f}, lsB[2] = {0.f, 0.f};
    unsigned short* Pw = PlB + w * (32 * 64);

    asm volatile("s_waitcnt vmcnt(0) lgkmcnt(0)" ::: "memory");
    __builtin_amdgcn_s_barrier();

#pragma unroll 1
    for (int t = 0; t < 32; t++) {
        int k0 = t * 64;
        if (t + 1 < 32)
            stage_kv(Kb, Vtb, k0 + 64, KsB + ((t + 1) & 1) * 4096,
                     VsB + ((t + 1) & 1) * 4096, tid);
        __builtin_amdgcn_sched_barrier(0);
        const unsigned short* Kc = KsB + (t & 1) * 4096;
        const unsigned short* Vc = VsB + (t & 1) * 4096;
#pragma unroll
        for (int fk = 0; fk < 4; fk++) {
            int row = fk * 16 + li;
            bf16x8 kf0 = *(const bf16x8*)(Kc + row * 64 + ((lg * 8) ^ sw));
            bf16x8 kf1 = *(const bf16x8*)(Kc + row * 64 + ((32 + lg * 8) ^ sw));
            floatv4 mk = *(const floatv4*)(Ml + k0 + fk * 16 + lg * 4);
#pragma unroll
            for (int fq = 0; fq < 2; fq++) {
                f32x4 sc = f32x4{0.f, 0.f, 0.f, 0.f};
                sc = MFMA16(kf0, qa[fq][0], sc);
                sc = MFMA16(kf1, qa[fq][1], sc);
                floatv4 pv;
#pragma unroll
                for (int r = 0; r < 4; r++)
                    pv[r] = __expf(fminf(sc[r] + mk[r], 80.f));
                lsA[fq] += pv[0] + pv[1];
                lsB[fq] += pv[2] + pv[3];
                ushortv4 pk;
#pragma unroll
                for (int r = 0; r < 4; r++) pk[r] = f2bf_trunc(pv[r]);
                *(ushortv4*)(Pw + (fq * 16 + li) * 64 + ((fk * 16 + lg * 4) ^ sw)) = pk;
            }
        }
        // PV: pure-MFMA cluster under raised priority (T5)
        __builtin_amdgcn_s_setprio(1);
#pragma unroll
        for (int kc = 0; kc < 2; kc++) {
            bf16x8 vf[4];
#pragma unroll
            for (int gd = 0; gd < 4; gd++) {
                int vrow = gd * 16 + li;
                vf[gd] = *(const bf16x8*)(Vc + vrow * 64 + ((kc * 32 + lg * 8) ^ sw));
            }
#pragma unroll
            for (int fq = 0; fq < 2; fq++) {
                bf16x8 pa = *(const bf16x8*)(Pw + (fq * 16 + li) * 64 +
                                             ((kc * 32 + lg * 8) ^ sw));
#pragma unroll
                for (int gd = 0; gd < 4; gd++)
                    oacc[fq][gd] = MFMA16(pa, vf[gd], oacc[fq][gd]);
            }
        }
        __builtin_amdgcn_s_setprio(0);
        asm volatile("s_waitcnt vmcnt(0)" ::: "memory");
        __builtin_amdgcn_s_barrier();
    }

    // linv per (fq, li); broadcast to D-layout rows via per-wave LDS
    float linvv[2];
    float* LinvW = (float*)Pw;  // Pl[w] dead now
#pragma unroll
    for (int fq = 0; fq < 2; fq++) {
        float lsum = lsA[fq] + lsB[fq];
        lsum += __shfl_xor(lsum, 16);
        lsum += __shfl_xor(lsum, 32);
        linvv[fq] = 1.0f / lsum;
        if (lg == 0) LinvW[fq * 16 + li] = linvv[fq];
    }
    int h = bh & 15;
#pragma unroll
    for (int fq = 0; fq < 2; fq++)
#pragma unroll
        for (int gd = 0; gd < 4; gd++)
#pragma unroll
            for (int r = 0; r < 4; r++) {
                int srow = qw + fq * 16 + lg * 4 + r;
                float o = oacc[fq][gd][r] * LinvW[fq * 16 + lg * 4 + r];
                Ob[(size_t)(b * SS + srow) * DMODEL + h * 64 + gd * 16 + li] = f2bf(o);
            }

    // ---- pass B: pipelined compute/store via per-wave Pt double buffer ----
    __builtin_amdgcn_s_barrier();  // all waves done with PlB (LinvW) + Ks/Vs
    float* PtW = (float*)SH + w * 4096;   // 2 x 2048 f32 per wave (16KB)
    int rgrp = lane >> 4;
    float* arowbase = attn_out + ((size_t)bh * SS + qw) * SS;

#pragma unroll 1
    for (int t = 0; t < 32; t++) {
        int k0 = t * 64;
        float* Pt = PtW + (t & 1) * 2048;
        // compute tile t -> Pt[t&1]
#pragma unroll
        for (int fk = 0; fk < 4; fk++) {
            const unsigned short* kp = Kb + (size_t)(k0 + fk * 16 + li) * 64;
            bf16x8 kf0 = *(const bf16x8*)(kp + lg * 8);
            bf16x8 kf1 = *(const bf16x8*)(kp + 32 + lg * 8);
            floatv4 mk = *(const floatv4*)(Ml + k0 + fk * 16 + lg * 4);
#pragma unroll
            for (int fq = 0; fq < 2; fq++) {
                __builtin_amdgcn_s_setprio(1);
                f32x4 sc = f32x4{0.f, 0.f, 0.f, 0.f};
                sc = MFMA16(kf0, qa[fq][0], sc);
                sc = MFMA16(kf1, qa[fq][1], sc);
                __builtin_amdgcn_s_setprio(0);
                floatv4 pv;
#pragma unroll
                for (int r = 0; r < 4; r++)
                    pv[r] = __expf(fminf(sc[r] + mk[r], 80.f)) * linvv[fq];
                int prow = fq * 16 + li;
                *(floatv4*)(Pt + prow * 64 + ((fk * 16 + lg * 4) ^ ((prow & 7) << 3))) = pv;
            }
        }
        // store tile t-1 from the other buffer (coalesced 4 rows x 256B, nontemporal)
        if (t > 0) {
            float* Pp = PtW + ((t & 1) ^ 1) * 2048;
            int pk0 = k0 - 64;
#pragma unroll
            for (int g = 0; g < 8; g++) {
                int row = g * 4 + rgrp;
                int colb = li * 4;
                floatv4 vv = *(const floatv4*)(Pp + row * 64 + (colb ^ ((row & 7) << 3)));
                __builtin_nontemporal_store(
                    vv, (floatv4*)(arowbase + (size_t)row * SS + pk0 + colb));
            }
        }
    }
    // epilogue: store tile 31
    {
        float* Pp = PtW + 2048;  // (31&1)=1
        int pk0 = 31 * 64;
#pragma unroll
        for (int g = 0; g < 8; g++) {
            int row = g * 4 + rgrp;
            int colb = li * 4;
            floatv4 vv = *(const floatv4*)(Pp + row * 64 + (colb ^ ((row & 7) << 3)));
            __builtin_nontemporal_store(
                vv, (floatv4*)(arowbase + (size_t)row * SS + pk0 + colb));
        }
    }
}

// ---------------- LayerNorm (bias + residual folded in; Yb is bf16) ----------------
__global__ __launch_bounds__(256) void ln_kernel(const unsigned short* __restrict__ Yb,
                                                 const float* __restrict__ qres,
                                                 const float* __restrict__ bo,
                                                 const float* __restrict__ gamma,
                                                 const float* __restrict__ beta,
                                                 float* __restrict__ out) {
    int row = blockIdx.x;
    int t = threadIdx.x;
    ushortv4 yv = ((const ushortv4*)(Yb + (size_t)row * DMODEL))[t];
    floatv4 qv = ((const floatv4*)(qres + (size_t)row * DMODEL))[t];
    floatv4 bv = ((const floatv4*)bo)[t];
    floatv4 v;
    v.x = bf2f(yv.x) + bv.x + qv.x;
    v.y = bf2f(yv.y) + bv.y + qv.y;
    v.z = bf2f(yv.z) + bv.z + qv.z;
    v.w = bf2f(yv.w) + bv.w + qv.w;
    float s1 = v.x + v.y + v.z + v.w;
    float s2 = v.x * v.x + v.y * v.y + v.z * v.z + v.w * v.w;
#pragma unroll
    for (int m = 1; m < 64; m <<= 1) { s1 += __shfl_xor(s1, m); s2 += __shfl_xor(s2, m); }
    __shared__ float red[8];
    int w = t >> 6, lane = t & 63;
    if (lane == 0) { red[w] = s1; red[4 + w] = s2; }
    __syncthreads();
    s1 = red[0] + red[1] + red[2] + red[3];
    s2 = red[4] + red[5] + red[6] + red[7];
    float mu = s1 * (1.0f / DMODEL);
    float var = s2 * (1.0f / DMODEL) - mu * mu;
    float rstd = rsqrtf(var + 1e-5f);
    floatv4 g = ((const floatv4*)gamma)[t];
    floatv4 bb = ((const floatv4*)beta)[t];
    floatv4 o;
    o.x = (v.x - mu) * rstd * g.x + bb.x;
    o.y = (v.y - mu) * rstd * g.y + bb.y;
    o.z = (v.z - mu) * rstd * g.z + bb.z;
    o.w = (v.w - mu) * rstd * g.w + bb.w;
    __builtin_nontemporal_store(o, (floatv4*)(out + (size_t)row * DMODEL) + t);
}

// ---------------- launch ----------------
extern "C" void kernel_launch(void* const* d_in, const int* in_sizes, int n_in,
                              void* d_out, int out_size, void* d_ws, size_t ws_size,
                              hipStream_t stream) {
    const float* q = (const float*)d_in[0];
    const float* k = (const float*)d_in[1];
    const float* v = (const float*)d_in[2];
    const int* mask = (const int*)d_in[3];
    const float* Wq = (const float*)d_in[4];
    const float* Wk = (const float*)d_in[5];
    const float* Wv = (const float*)d_in[6];
    const float* Wo = (const float*)d_in[7];
    const float* bo = (const float*)d_in[8];
    const float* gamma = (const float*)d_in[9];
    const float* beta = (const float*)d_in[10];

    float* out = (float*)d_out;
    float* attn = out + (size_t)BB * SS * DMODEL;

    const size_t NTOK = (size_t)BB * SS;          // 4096
    unsigned short* qb = (unsigned short*)d_ws;   // [4096][1024] bf16
    unsigned short* kb = qb + NTOK * DMODEL;
    unsigned short* vb = kb + NTOK * DMODEL;
    unsigned short* Wqt = vb + NTOK * DMODEL;     // [1024][1024] bf16 (transposed)
    unsigned short* Wkt = Wqt + (size_t)DMODEL * DMODEL;
    unsigned short* Wvt = Wkt + (size_t)DMODEL * DMODEL;
    unsigned short* Wot = Wvt + (size_t)DMODEL * DMODEL;
    unsigned short* Qp = Wot + (size_t)DMODEL * DMODEL;  // [B,H,S,64] bf16 (pre-scaled)
    unsigned short* Kp = Qp + NTOK * DMODEL;
    unsigned short* Vt = Kp + NTOK * DMODEL;      // [B,H,64,S] bf16 (transposed)
    unsigned short* Ob = Vt + NTOK * DMODEL;      // [4096][1024] bf16
    unsigned short* Yb = qb;                      // reuse qb region post-attention (bf16)

    prep<<<16384, 256, 0, stream>>>(q, k, v, qb, kb, vb, Wq, Wk, Wv, Wo,
                                    Wqt, Wkt, Wvt, Wot);

    gemm_qkv<<<dim3(24, 32), 256, 0, stream>>>(qb, kb, vb, Wqt, Wkt, Wvt, Qp, Kp, Vt);

    attn_fused<<<512, 256, 0, stream>>>(Qp, Kp, Vt, mask, attn, Ob);

    gemm_out<<<dim3(8, 32), 256, 0, stream>>>(Ob, Wot, Yb);

    ln_kernel<<<(int)NTOK, 256, 0, stream>>>(Yb, q, bo, gamma, beta, out);
}